// Round 7
// baseline (216.574 us; speedup 1.0000x reference)
//
#include <hip/hip_runtime.h>
#include <hip/hip_bf16.h>
#include <stdint.h>

typedef __hip_bfloat16 bf16;
typedef __attribute__((ext_vector_type(8))) short short8;
typedef __attribute__((ext_vector_type(4))) short short4v;
typedef __attribute__((ext_vector_type(4))) float float4v;

static constexpr int nB = 2, nS = 2048, nD = 1024, nH = 16, nHD = 64;
static constexpr int nBS = nB * nS;   // 4096

#define AS_GLOBAL __attribute__((address_space(1)))
#define AS_LDS    __attribute__((address_space(3)))

union Frag16B { short8 v; uint4 u4; uint2 u2[2]; };

__device__ __forceinline__ void gload_lds16(const void* g, void* l) {
  __builtin_amdgcn_global_load_lds((AS_GLOBAL uint32_t*)(g), (AS_LDS uint32_t*)(l), 16, 0, 0);
}

__device__ __forceinline__ float fast_exp2(float x) {
#if __has_builtin(__builtin_amdgcn_exp2f)
  return __builtin_amdgcn_exp2f(x);
#else
  float r; asm volatile("v_exp_f32 %0, %1" : "=v"(r) : "v"(x)); return r;
#endif
}

// drain LDS ops but NOT vmem: prefetch global loads stay in flight across the barrier
__device__ __forceinline__ void lds_barrier() {
  asm volatile("s_waitcnt lgkmcnt(0)\ns_barrier" ::: "memory");
}

__device__ __forceinline__ void lgkm_wait() {
  asm volatile("s_waitcnt lgkmcnt(0)" ::: "memory");
}

// ---------------------------------------------------------------- prep: cast QKV->bf16, W->W^T bf16, rope tables
__global__ __launch_bounds__(256) void prep_kernel(
    const float* __restrict__ Qin, const float* __restrict__ Kin, const float* __restrict__ Vin,
    const float* __restrict__ Wq, const float* __restrict__ Wk,
    const float* __restrict__ Wv, const float* __restrict__ Wo,
    bf16* __restrict__ Qbf, bf16* __restrict__ Kbf, bf16* __restrict__ Vbf,
    bf16* __restrict__ WqT, bf16* __restrict__ WkT, bf16* __restrict__ WvT, bf16* __restrict__ WoT,
    bf16* __restrict__ cos_t, bf16* __restrict__ sin_t) {
  __shared__ float tile[64][65];
  int bx = blockIdx.x, t = threadIdx.x;
  if (bx < 3072) {
    int tz = bx >> 10, blk = bx & 1023;
    const float* src = tz == 0 ? Qin : tz == 1 ? Kin : Vin;
    bf16* dst = tz == 0 ? Qbf : tz == 1 ? Kbf : Vbf;
#pragma unroll
    for (int i = 0; i < 4; ++i) {
      int idx = blk * 1024 + i * 256 + t;  // float4 index
      float4 v = ((const float4*)src)[idx];
      union { bf16 b[4]; uint2 u; } tmp;
      tmp.b[0] = __float2bfloat16(v.x);
      tmp.b[1] = __float2bfloat16(v.y);
      tmp.b[2] = __float2bfloat16(v.z);
      tmp.b[3] = __float2bfloat16(v.w);
      ((uint2*)dst)[idx] = tmp.u;
    }
  } else if (bx < 4096) {
    int idx = bx - 3072;
    int z = idx >> 8;
    const float* W = z == 0 ? Wq : z == 1 ? Wk : z == 2 ? Wv : Wo;
    bf16* T = z == 0 ? WqT : z == 1 ? WkT : z == 2 ? WvT : WoT;
    int tk = (idx & 15) * 64, tn = ((idx >> 4) & 15) * 64;
    int c = t & 63, r0 = t >> 6;
#pragma unroll
    for (int i = 0; i < 16; ++i) {
      int r = i * 4 + r0;
      tile[r][c] = W[(size_t)(tk + r) * nD + tn + c];
    }
    __syncthreads();
#pragma unroll
    for (int i = 0; i < 16; ++i) {
      int r = i * 4 + r0;
      T[(size_t)(tn + r) * nD + tk + c] = __float2bfloat16(tile[c][r]);
    }
  } else {
    int base = (bx - 4096) * 1024 + t * 4;
#pragma unroll
    for (int i = 0; i < 4; ++i) {
      int e = base + i;
      int s = e >> 5, j = e & 31;
      float inv_freq = powf(100000.0f, -(float)(2 * j) / 64.0f);
      float g = (float)s * inv_freq;
      cos_t[e] = __float2bfloat16(cosf(g));
      sin_t[e] = __float2bfloat16(sinf(g));
    }
  }
}

// ---------------------------------------------------------------- fused projection GEMM v3: 128x128 tile, BK=64,
// 4 waves (2Mx2N, each 64x64), DOUBLE-BUFFERED 64 KiB LDS, ONE barrier per K-step (16 total).
// Step T: stage tile T+1 -> nx (8 gloads, issued first) | 16 ds_read + 32 MFMA on cu |
//         vmcnt(0) (T+1 landed after full-compute-phase flight) | barrier.
// Safety: cu's reads are consumed by this step's MFMAs before the barrier, so next step's
// stores into cu (= its nx) can't race. Grid 768 flattened, bijective XCD swizzle.
__global__ __launch_bounds__(256, 2) void gemm_qkv_kernel(
    const bf16* __restrict__ A0, const bf16* __restrict__ A1, const bf16* __restrict__ A2,
    const bf16* __restrict__ Bt0, const bf16* __restrict__ Bt1, const bf16* __restrict__ Bt2,
    bf16* __restrict__ q_h, bf16* __restrict__ k_h, bf16* __restrict__ vt_h,
    const bf16* __restrict__ cos_t, const bf16* __restrict__ sin_t) {
  // flattened grid 768 = 3 z * 8 n * 32 m ; bijective XCD swizzle (768 % 8 == 0)
  const int bid = blockIdx.x;
  const int swz = (bid & 7) * 96 + (bid >> 3);
  const int z = swz >> 8;            // 0..2
  const int rem = swz & 255;
  const int n0 = (rem >> 5) * 128;   // 8 n-tiles
  const int m0 = (rem & 31) * 128;   // 32 m-tiles

  const bf16* __restrict__ A  = z == 0 ? A0 : (z == 1 ? A1 : A2);
  const bf16* __restrict__ Bt = z == 0 ? Bt0 : (z == 1 ? Bt1 : Bt2);

  __shared__ bf16 As[2 * 128 * 64];   // 32 KiB (two 16 KiB buffers)
  __shared__ bf16 Bs[2 * 128 * 64];   // 32 KiB

  const int t = threadIdx.x;          // 0..255
  const int lane = t & 63;
  const int wid = t >> 6;             // 0..3
  const int quad = lane >> 4;
  const int l16 = lane & 15;
  const int r7 = l16 & 7;
  const int wm = wid >> 1;            // 0..1 -> 64 rows each
  const int wn = wid & 1;             // 0..1 -> 64 cols each (one head per wave)

  // staging: issue i covers rows i*32 + (t>>3); LDS row R holds 64 k (8 chunks of 16B),
  // global chunk (t&7)^(R&7) -> LDS chunk (t&7) (linear dest, pre-swizzled source)
  const int srow = t >> 3;                       // 0..31
  const int scg8 = ((t & 7) ^ (srow & 7)) * 8;   // swizzled k-offset (elements)

  // fragment-read offsets: row = {wm|wn}*64 + mi*16 + l16, chunk = (kk*4+quad) ^ r7
  const int ch0 = (quad ^ r7) * 8;
  const int ch1 = ch0 ^ 32;
  const int arow = (wm * 64 + l16) * 64;   // + mi*1024 (+buf)
  const int brow = (wn * 64 + l16) * 64;   // + ni*1024 (+buf)

#define STAGE(KT, BUF) do { \
    const bf16* ag_ = A + (size_t)(m0 + srow) * nD + (KT) * 64 + scg8; \
    const bf16* bg_ = Bt + (size_t)(n0 + srow) * nD + (KT) * 64 + scg8; \
    _Pragma("unroll") \
    for (int i = 0; i < 4; ++i) { \
      gload_lds16(ag_ + (size_t)(i * 32) * nD, As + (BUF) + i * 2048 + wid * 512); \
      gload_lds16(bg_ + (size_t)(i * 32) * nD, Bs + (BUF) + i * 2048 + wid * 512); \
    } \
  } while (0)

  float4v acc[4][4] = {};

  // prologue: tile 0 -> buf0
  STAGE(0, 0);
  asm volatile("s_waitcnt vmcnt(0)" ::: "memory");
  __builtin_amdgcn_s_barrier();

#pragma unroll 2
  for (int T = 0; T < 16; ++T) {
    const int cu = (T & 1) * 8192;
    const int nx = cu ^ 8192;

    if (T < 15) STAGE(T + 1, nx);

    Frag16B fa0[4], fa1[4], fb0[4], fb1[4];
#pragma unroll
    for (int mi = 0; mi < 4; ++mi) {
      fa0[mi].u4 = *(const uint4*)&As[cu + arow + mi * 1024 + ch0];
      fa1[mi].u4 = *(const uint4*)&As[cu + arow + mi * 1024 + ch1];
    }
#pragma unroll
    for (int ni = 0; ni < 4; ++ni) {
      fb0[ni].u4 = *(const uint4*)&Bs[cu + brow + ni * 1024 + ch0];
      fb1[ni].u4 = *(const uint4*)&Bs[cu + brow + ni * 1024 + ch1];
    }

    __builtin_amdgcn_s_setprio(1);
#pragma unroll
    for (int mi = 0; mi < 4; ++mi)
#pragma unroll
      for (int ni = 0; ni < 4; ++ni)
        acc[mi][ni] = __builtin_amdgcn_mfma_f32_16x16x32_bf16(fa0[mi].v, fb0[ni].v, acc[mi][ni], 0, 0, 0);
#pragma unroll
    for (int mi = 0; mi < 4; ++mi)
#pragma unroll
      for (int ni = 0; ni < 4; ++ni)
        acc[mi][ni] = __builtin_amdgcn_mfma_f32_16x16x32_bf16(fa1[mi].v, fb1[ni].v, acc[mi][ni], 0, 0, 0);
    __builtin_amdgcn_s_setprio(0);

    asm volatile("s_waitcnt vmcnt(0)" ::: "memory");
    __builtin_amdgcn_s_barrier();
  }
#undef STAGE

  // ---- epilogue: RoPE + RMSNorm (q,k) or transposed store (v)
  const int col0 = n0 + wn * 64;   // multiple of 64 -> one head per wave
  if (z <= 1) {
    bf16* dst = z ? k_h : q_h;
#pragma unroll
    for (int mi = 0; mi < 4; ++mi)
#pragma unroll
      for (int r = 0; r < 4; ++r) {
        int row = m0 + wm * 64 + mi * 16 + quad * 4 + r;
        int s = row & (nS - 1);
        float x0 = acc[mi][0][r], x1 = acc[mi][1][r], x2 = acc[mi][2][r], x3 = acc[mi][3][r];
        float y[4];
#pragma unroll
        for (int p = 0; p < 2; ++p) {
          int d = p * 16 + l16;
          float c = __bfloat162float(cos_t[s * 32 + d]);
          float sn = __bfloat162float(sin_t[s * 32 + d]);
          float xa = p ? x1 : x0, xb = p ? x3 : x2;
          y[p] = xa * c + xb * sn;
          y[p + 2] = xb * c - xa * sn;
        }
        float ss = y[0] * y[0] + y[1] * y[1] + y[2] * y[2] + y[3] * y[3];
#pragma unroll
        for (int m = 1; m <= 8; m <<= 1) ss += __shfl_xor(ss, m, 64);
        float inv = 1.0f / sqrtf(ss * (1.0f / 64.0f) + 1e-9f);
#pragma unroll
        for (int ni = 0; ni < 4; ++ni)
          dst[(size_t)row * nD + col0 + ni * 16 + l16] = __float2bfloat16(y[ni] * inv);
      }
  } else {
    // V: write transposed -> vt_h [b][h][d][s]
#pragma unroll
    for (int mi = 0; mi < 4; ++mi)
#pragma unroll
      for (int r = 0; r < 4; ++r) {
        int row = m0 + wm * 64 + mi * 16 + quad * 4 + r;
        int b = row >> 11, s = row & (nS - 1);
#pragma unroll
        for (int ni = 0; ni < 4; ++ni) {
          int col = col0 + ni * 16 + l16;
          int h = col >> 6, d = col & 63;
          vt_h[((size_t)((b * nH + h) * 64 + d)) * nS + s] = __float2bfloat16(acc[mi][ni][r]);
        }
      }
  }
}

// ---------------------------------------------------------------- output GEMM v2: 64x128 tile, BK=64,
// double-buffered 48 KiB LDS, ONE barrier per K-step. Grid 512 flattened, n-major (bid&7 = n-tile)
// so same-B-panel blocks land on the same XCD under round-robin dispatch.
__global__ __launch_bounds__(256, 2) void gemm_out_kernel(
    const bf16* __restrict__ A, const bf16* __restrict__ Bt, float* __restrict__ C) {
  __shared__ bf16 As[2 * 64 * 64];    // 16 KiB
  __shared__ bf16 Bs[2 * 128 * 64];   // 32 KiB
  const int bid = blockIdx.x;         // 0..511
  const int n0 = (bid & 7) * 128;
  const int m0 = (bid >> 3) * 64;
  const int t = threadIdx.x;
  const int lane = t & 63;
  const int wid = t >> 6;
  const int quad = lane >> 4;
  const int l16 = lane & 15;
  const int r7 = l16 & 7;
  const int wm = wid >> 1;
  const int wn = wid & 1;

  const int srow = t >> 3;                       // 0..31
  const int scg8 = ((t & 7) ^ (srow & 7)) * 8;

  const int ch0 = (quad ^ r7) * 8;
  const int ch1 = ch0 ^ 32;
  const int arow = (wm * 32 + l16) * 64;   // + mi*1024 (+buf)
  const int brow = (wn * 64 + l16) * 64;   // + ni*1024 (+buf)

#define STAGE_O(KT, AB, BB) do { \
    const bf16* ag_ = A + (size_t)(m0 + srow) * nD + (KT) * 64 + scg8; \
    const bf16* bg_ = Bt + (size_t)(n0 + srow) * nD + (KT) * 64 + scg8; \
    gload_lds16(ag_, As + (AB) + wid * 512); \
    gload_lds16(ag_ + (size_t)32 * nD, As + (AB) + 2048 + wid * 512); \
    _Pragma("unroll") \
    for (int i = 0; i < 4; ++i) \
      gload_lds16(bg_ + (size_t)(i * 32) * nD, Bs + (BB) + i * 2048 + wid * 512); \
  } while (0)

  float4v acc[2][4] = {};

  STAGE_O(0, 0, 0);
  asm volatile("s_waitcnt vmcnt(0)" ::: "memory");
  __builtin_amdgcn_s_barrier();

#pragma unroll 2
  for (int T = 0; T < 16; ++T) {
    const int cua = (T & 1) * 4096;
    const int cub = (T & 1) * 8192;

    if (T < 15) STAGE_O(T + 1, cua ^ 4096, cub ^ 8192);

    Frag16B a0[2], a1[2], b0[4], b1[4];
#pragma unroll
    for (int mi = 0; mi < 2; ++mi) {
      a0[mi].u4 = *(const uint4*)&As[cua + arow + mi * 1024 + ch0];
      a1[mi].u4 = *(const uint4*)&As[cua + arow + mi * 1024 + ch1];
    }
#pragma unroll
    for (int ni = 0; ni < 4; ++ni) {
      b0[ni].u4 = *(const uint4*)&Bs[cub + brow + ni * 1024 + ch0];
      b1[ni].u4 = *(const uint4*)&Bs[cub + brow + ni * 1024 + ch1];
    }

    __builtin_amdgcn_s_setprio(1);
#pragma unroll
    for (int mi = 0; mi < 2; ++mi)
#pragma unroll
      for (int ni = 0; ni < 4; ++ni)
        acc[mi][ni] = __builtin_amdgcn_mfma_f32_16x16x32_bf16(a0[mi].v, b0[ni].v, acc[mi][ni], 0, 0, 0);
#pragma unroll
    for (int mi = 0; mi < 2; ++mi)
#pragma unroll
      for (int ni = 0; ni < 4; ++ni)
        acc[mi][ni] = __builtin_amdgcn_mfma_f32_16x16x32_bf16(a1[mi].v, b1[ni].v, acc[mi][ni], 0, 0, 0);
    __builtin_amdgcn_s_setprio(0);

    asm volatile("s_waitcnt vmcnt(0)" ::: "memory");
    __builtin_amdgcn_s_barrier();
  }
#undef STAGE_O

#pragma unroll
  for (int mi = 0; mi < 2; ++mi)
#pragma unroll
    for (int ni = 0; ni < 4; ++ni)
#pragma unroll
      for (int r = 0; r < 4; ++r) {
        int row = m0 + wm * 32 + mi * 16 + quad * 4 + r;
        int col = n0 + wn * 64 + ni * 16 + l16;
        C[(size_t)row * nD + col] = acc[mi][ni][r];
      }
}

// ---------------------------------------------------------------- flash attention v8: KVBLK=128, 8-wave blocks,
// wave owns 16 q-rows. Main loop = full unmasked 128-key tiles (branchless); final diagonal tile
// handles all masking. K/V via global_load_lds, double-buffered 64 KiB LDS (2 blocks/CU),
// one vmcnt(0)+lgkm(0)+barrier per 128 keys.
static constexpr float SC = 0.18033688011112042f;  // 0.125 * log2(e)

__global__ __launch_bounds__(512, 4) void attn_kernel(const bf16* __restrict__ q_h,
                                                      const bf16* __restrict__ k_h,
                                                      const bf16* __restrict__ vt_h,
                                                      bf16* __restrict__ vals) {
  __shared__ bf16 lds_buf[4 * 8192];   // [K0|K1|V0|V1], 8192 elems each: K=128x64, V=2 half-subtiles 64x64

  const int t = threadIdx.x;           // 0..511
  const int lane = t & 63, wid = t >> 6, quad = lane >> 4, l16 = lane & 15;
  const int id = blockIdx.x;           // 0..511
  const int xcd = id & 7;              // round-robin XCD heuristic
  const int j = id >> 3;               // 0..63 per-XCD index
  const int jj = j & 31;
  const int bh = xcd * 4 + (jj & 3);   // 4 heads per XCD; pair blocks share bh
  const int u = jj >> 2;               // 0..7
  const int qt = (j < 32) ? (15 - u) : u;   // first CU-slot: long tiles; second: complementary short
  const int b = bh >> 4, h = bh & 15;

  const bf16* Kbase = k_h + ((size_t)b * nS) * nD + h * 64;
  const bf16* Vbase = vt_h + (size_t)bh * 64 * nS;  // [d][s]

  const int rl = lane >> 3;               // 0..7
  const int cg8 = ((lane & 7) ^ rl) * 8;  // pre-swizzled source chunk (elem offset)
  const int r7 = l16 & 7;

  bf16* const scratch = lds_buf + wid * 1152;  // 16 x 72 per wave (epilogue only)

  const int q0w = qt * 128 + wid * 16;         // wave's first q row

  // Q B-frags (col=q=l16, k=d), 2 d-halves
  Frag16B qf[2];
  {
    const bf16* qp = q_h + ((size_t)(b * nS + q0w + l16)) * nD + h * 64;
    qf[0].u4 = *(const uint4*)(qp + quad * 8);
    qf[1].u4 = *(const uint4*)(qp + 32 + quad * 8);
  }

  // stage 128-key K/V tile KT into buffer (KT&1): linear LDS dest, swizzled global source
#define STAGE_KV(KT) do { \
    const int bo_ = ((KT) & 1) * 8192; \
    const bf16* kg_ = Kbase + (size_t)((KT) * 128 + wid * 16 + rl) * nD + cg8; \
    gload_lds16(kg_, lds_buf + bo_ + wid * 1024); \
    gload_lds16(kg_ + (size_t)8 * nD, lds_buf + bo_ + wid * 1024 + 512); \
    const bf16* vg_ = Vbase + (size_t)(wid * 8 + rl) * nS + (KT) * 128 + cg8; \
    gload_lds16(vg_, lds_buf + 16384 + bo_ + wid * 512); \
    gload_lds16(vg_ + 64, lds_buf + 16384 + bo_ + 4096 + wid * 512); \
  } while (0)

  // QK^T for half HB of current K tile -> ST (S^T frags, key=row)
#define QKH(Kb, HB, ST) do { \
    _Pragma("unroll") \
    for (int kt4 = 0; kt4 < 4; ++kt4) { \
      int row = (HB) * 64 + kt4 * 16 + l16; \
      Frag16B k0_, k1_; \
      k0_.u4 = *(const uint4*)&(Kb)[row * 64 + ((quad ^ r7) * 8)]; \
      k1_.u4 = *(const uint4*)&(Kb)[row * 64 + (((quad + 4) ^ r7) * 8)]; \
      float4v zz_ = {}; \
      zz_ = __builtin_amdgcn_mfma_f32_16x16x32_bf16(k0_.v, qf[0].v, zz_, 0, 0, 0); \
      (ST)[kt4] = __builtin_amdgcn_mfma_f32_16x16x32_bf16(k1_.v, qf[1].v, zz_, 0, 0, 0); \
    } \
  } while (0)

  // exp (unmasked) ST -> PF, accumulate l_acc
#define EXPH(ST, PF) do { \
    _Pragma("unroll") \
    for (int kt4 = 0; kt4 < 4; ++kt4) \
      _Pragma("unroll") \
      for (int r = 0; r < 4; ++r) { \
        float p_ = fast_exp2((ST)[kt4][r] * SC); \
        l_acc += p_; \
        union { bf16 hh; short ss; } cv_; \
        cv_.hh = __float2bfloat16(p_); \
        (PF)[kt4][r] = cv_.ss; \
      } \
  } while (0)

  // exp (masked, diagonal tile) for half HB
#define EXPHM(ST, PF, HB) do { \
    int qg_ = q0w + l16; \
    _Pragma("unroll") \
    for (int kt4 = 0; kt4 < 4; ++kt4) { \
      int key0_ = qt * 128 + (HB) * 64 + kt4 * 16 + quad * 4; \
      _Pragma("unroll") \
      for (int r = 0; r < 4; ++r) { \
        float x_ = (ST)[kt4][r] * SC; \
        if (key0_ + r > qg_) x_ = -12000.0f; \
        float p_ = fast_exp2(x_); \
        l_acc += p_; \
        union { bf16 hh; short ss; } cv_; \
        cv_.hh = __float2bfloat16(p_); \
        (PF)[kt4][r] = cv_.ss; \
      } \
    } \
  } while (0)

  // O^T += V^T(half HB) . P^T
#define PVH(Vb, HB, PF) do { \
    _Pragma("unroll") \
    for (int dt = 0; dt < 4; ++dt) { \
      int row = dt * 16 + l16; \
      _Pragma("unroll") \
      for (int kt4 = 0; kt4 < 4; ++kt4) { \
        int chunk_ = kt4 * 2 + (quad >> 1); \
        union { uint2 u; short4v s; } vv_; \
        vv_.u = *(const uint2*)&(Vb)[(HB) * 4096 + row * 64 + ((chunk_ ^ r7) * 8) + (quad & 1) * 4]; \
        o_acc[dt] = __builtin_amdgcn_mfma_f32_16x16x16bf16_1k(vv_.s, (PF)[kt4], o_acc[dt], 0, 0, 0); \
      } \
    } \
  } while (0)

  STAGE_KV(0);
  asm volatile("s_waitcnt vmcnt(0)" ::: "memory");
  __builtin_amdgcn_s_barrier();

  float4v o_acc[4] = {};
  float l_acc = 0.f;

  // ---- main loop: full unmasked tiles (branchless)
  for (int kt = 0; kt < qt; ++kt) {
    STAGE_KV(kt + 1);
    const bf16* Kb = lds_buf + (kt & 1) * 8192;
    const bf16* Vb = lds_buf + 16384 + (kt & 1) * 8192;

    float4v st0[4], st1[4];
    __builtin_amdgcn_s_setprio(1);
    QKH(Kb, 0, st0);
    QKH(Kb, 1, st1);
    __builtin_amdgcn_s_setprio(0);

    short4v pf[4];
    EXPH(st0, pf);
    __builtin_amdgcn_s_setprio(1);
    PVH(Vb, 0, pf);
    __builtin_amdgcn_s_setprio(0);
    EXPH(st1, pf);
    __builtin_amdgcn_s_setprio(1);
    PVH(Vb, 1, pf);
    __builtin_amdgcn_s_setprio(0);

    asm volatile("s_waitcnt vmcnt(0) lgkmcnt(0)" ::: "memory");
    __builtin_amdgcn_s_barrier();
  }

  // ---- final diagonal tile kt = qt (no prefetch; all masking lives here)
  {
    const bf16* Kb = lds_buf + (qt & 1) * 8192;
    const bf16* Vb = lds_buf + 16384 + (qt & 1) * 8192;

    float4v st0[4];
    QKH(Kb, 0, st0);
    short4v pf[4];
    EXPHM(st0, pf, 0);
    PVH(Vb, 0, pf);

    if (wid >= 4) {   // waves 0-3: h1 keys are all > q0w+15 (fully masked) -> skip
      float4v st1[4];
      QKH(Kb, 1, st1);
      EXPHM(st1, pf, 1);
      PVH(Vb, 1, pf);
    }
  }
#undef STAGE_KV
#undef QKH
#undef EXPH
#undef EXPHM
#undef PVH

  // all waves done reading K/V before scratch (overlapping K region) is overwritten
  lds_barrier();

  // ---- epilogue: row-sum reduce, LDS-transpose, coalesced 16B stores
  float la = l_acc;
  la += __shfl_xor(la, 16, 64);
  la += __shfl_xor(la, 32, 64);
  float inv_l = 1.0f / la;
  // write transposed: scratch[q_loc=l16][d]
#pragma unroll
  for (int dt = 0; dt < 4; ++dt) {
    union { bf16 b2[2]; uint u; } p01, p23;
    p01.b2[0] = __float2bfloat16(o_acc[dt][0] * inv_l);
    p01.b2[1] = __float2bfloat16(o_acc[dt][1] * inv_l);
    p23.b2[0] = __float2bfloat16(o_acc[dt][2] * inv_l);
    p23.b2[1] = __float2bfloat16(o_acc[dt][3] * inv_l);
    *(uint*)&scratch[l16 * 72 + dt * 16 + quad * 4] = p01.u;
    *(uint*)&scratch[l16 * 72 + dt * 16 + quad * 4 + 2] = p23.u;
  }
  lgkm_wait();  // own writes visible to own reads
  uint4 r0 = *(const uint4*)&scratch[l16 * 72 + quad * 16];
  uint4 r1 = *(const uint4*)&scratch[l16 * 72 + quad * 16 + 8];
  int qrow = q0w + l16;
  bf16* vp = vals + ((size_t)(b * nS + qrow)) * nD + h * 64 + quad * 16;
  *(uint4*)(vp) = r0;
  *(uint4*)(vp + 8) = r1;
}

// ---------------------------------------------------------------- launch
extern "C" void kernel_launch(void* const* d_in, const int* in_sizes, int n_in,
                              void* d_out, int out_size, void* d_ws, size_t ws_size,
                              hipStream_t stream) {
  const float* Qin = (const float*)d_in[0];
  const float* Kin = (const float*)d_in[1];
  const float* Vin = (const float*)d_in[2];
  const float* Wq = (const float*)d_in[4];
  const float* Wk = (const float*)d_in[5];
  const float* Wv = (const float*)d_in[6];
  const float* Wo = (const float*)d_in[7];
  float* out = (float*)d_out;

  char* ws = (char*)d_ws;
  const size_t MB = 1u << 20;
  bf16* Qbf = (bf16*)(ws + 0 * MB);
  bf16* Kbf = (bf16*)(ws + 8 * MB);
  bf16* Vbf = (bf16*)(ws + 16 * MB);
  bf16* WqT = (bf16*)(ws + 24 * MB);
  bf16* WkT = (bf16*)(ws + 26 * MB);
  bf16* WvT = (bf16*)(ws + 28 * MB);
  bf16* WoT = (bf16*)(ws + 30 * MB);
  bf16* cos_t = (bf16*)(ws + 32 * MB);
  bf16* sin_t = (bf16*)(ws + 33 * MB);
  bf16* q_h = (bf16*)(ws + 34 * MB);
  bf16* k_h = (bf16*)(ws + 42 * MB);
  bf16* vt_h = (bf16*)(ws + 50 * MB);
  bf16* vals = (bf16*)(ws + 58 * MB);

  prep_kernel<<<4160, 256, 0, stream>>>(Qin, Kin, Vin, Wq, Wk, Wv, Wo,
                                        Qbf, Kbf, Vbf, WqT, WkT, WvT, WoT, cos_t, sin_t);

  gemm_qkv_kernel<<<768, 256, 0, stream>>>(Qbf, Kbf, Vbf, WqT, WkT, WvT,
                                           q_h, k_h, vt_h, cos_t, sin_t);

  attn_kernel<<<512, 512, 0, stream>>>(q_h, k_h, vt_h, vals);

  gemm_out_kernel<<<512, 256, 0, stream>>>(vals, WoT, out);
}

// Round 8
// 214.528 us; speedup vs baseline: 1.0095x; 1.0095x over previous
//
#include <hip/hip_runtime.h>
#include <hip/hip_bf16.h>
#include <stdint.h>

typedef __hip_bfloat16 bf16;
typedef __attribute__((ext_vector_type(8))) short short8;
typedef __attribute__((ext_vector_type(4))) short short4v;
typedef __attribute__((ext_vector_type(4))) float float4v;

static constexpr int nB = 2, nS = 2048, nD = 1024, nH = 16, nHD = 64;
static constexpr int nBS = nB * nS;   // 4096

#define AS_GLOBAL __attribute__((address_space(1)))
#define AS_LDS    __attribute__((address_space(3)))

union Frag16B { short8 v; uint4 u4; uint2 u2[2]; };

__device__ __forceinline__ void gload_lds16(const void* g, void* l) {
  __builtin_amdgcn_global_load_lds((AS_GLOBAL uint32_t*)(g), (AS_LDS uint32_t*)(l), 16, 0, 0);
}

__device__ __forceinline__ float fast_exp2(float x) {
#if __has_builtin(__builtin_amdgcn_exp2f)
  return __builtin_amdgcn_exp2f(x);
#else
  float r; asm volatile("v_exp_f32 %0, %1" : "=v"(r) : "v"(x)); return r;
#endif
}

// drain LDS ops but NOT vmem: prefetch global loads stay in flight across the barrier
__device__ __forceinline__ void lds_barrier() {
  asm volatile("s_waitcnt lgkmcnt(0)\ns_barrier" ::: "memory");
}

__device__ __forceinline__ void lgkm_wait() {
  asm volatile("s_waitcnt lgkmcnt(0)" ::: "memory");
}

// ---------------------------------------------------------------- prep: cast QKV->bf16, W->W^T bf16, rope tables
__global__ __launch_bounds__(256) void prep_kernel(
    const float* __restrict__ Qin, const float* __restrict__ Kin, const float* __restrict__ Vin,
    const float* __restrict__ Wq, const float* __restrict__ Wk,
    const float* __restrict__ Wv, const float* __restrict__ Wo,
    bf16* __restrict__ Qbf, bf16* __restrict__ Kbf, bf16* __restrict__ Vbf,
    bf16* __restrict__ WqT, bf16* __restrict__ WkT, bf16* __restrict__ WvT, bf16* __restrict__ WoT,
    bf16* __restrict__ cos_t, bf16* __restrict__ sin_t) {
  __shared__ float tile[64][65];
  int bx = blockIdx.x, t = threadIdx.x;
  if (bx < 3072) {
    int tz = bx >> 10, blk = bx & 1023;
    const float* src = tz == 0 ? Qin : tz == 1 ? Kin : Vin;
    bf16* dst = tz == 0 ? Qbf : tz == 1 ? Kbf : Vbf;
#pragma unroll
    for (int i = 0; i < 4; ++i) {
      int idx = blk * 1024 + i * 256 + t;  // float4 index
      float4 v = ((const float4*)src)[idx];
      union { bf16 b[4]; uint2 u; } tmp;
      tmp.b[0] = __float2bfloat16(v.x);
      tmp.b[1] = __float2bfloat16(v.y);
      tmp.b[2] = __float2bfloat16(v.z);
      tmp.b[3] = __float2bfloat16(v.w);
      ((uint2*)dst)[idx] = tmp.u;
    }
  } else if (bx < 4096) {
    int idx = bx - 3072;
    int z = idx >> 8;
    const float* W = z == 0 ? Wq : z == 1 ? Wk : z == 2 ? Wv : Wo;
    bf16* T = z == 0 ? WqT : z == 1 ? WkT : z == 2 ? WvT : WoT;
    int tk = (idx & 15) * 64, tn = ((idx >> 4) & 15) * 64;
    int c = t & 63, r0 = t >> 6;
#pragma unroll
    for (int i = 0; i < 16; ++i) {
      int r = i * 4 + r0;
      tile[r][c] = W[(size_t)(tk + r) * nD + tn + c];
    }
    __syncthreads();
#pragma unroll
    for (int i = 0; i < 16; ++i) {
      int r = i * 4 + r0;
      T[(size_t)(tn + r) * nD + tk + c] = __float2bfloat16(tile[c][r]);
    }
  } else {
    int base = (bx - 4096) * 1024 + t * 4;
#pragma unroll
    for (int i = 0; i < 4; ++i) {
      int e = base + i;
      int s = e >> 5, j = e & 31;
      float inv_freq = powf(100000.0f, -(float)(2 * j) / 64.0f);
      float g = (float)s * inv_freq;
      cos_t[e] = __float2bfloat16(cosf(g));
      sin_t[e] = __float2bfloat16(sinf(g));
    }
  }
}

// ---------------------------------------------------------------- fused projection GEMM v4: 128x128 tile, BK=32,
// 4 waves (2Mx2N, each 64x64), double-buffered 32 KiB LDS (round-6 footprint: 3 blocks/CU),
// ONE barrier per K-step (32 total, vs 96 in round 6's 3-phase).
// Step T (cu = T&1): stage A+B(T+1)->nx (4 gloads) | 8 ds_read + 16 MFMA on cu | vmcnt(0) | bar.
// Safety: cu's ds_reads are consumed by this step's MFMAs before the barrier, so next step's
// stores into cu can't race. LDS layout: paired rows (LDS row R = global rows {2R,2R+1} x 32 k),
// chunk c_orig = (m&1)*4 + kchunk stored at c_orig ^ (R&7). Grid 768 flattened, bijective XCD swizzle.
__global__ __launch_bounds__(256, 3) void gemm_qkv_kernel(
    const bf16* __restrict__ A0, const bf16* __restrict__ A1, const bf16* __restrict__ A2,
    const bf16* __restrict__ Bt0, const bf16* __restrict__ Bt1, const bf16* __restrict__ Bt2,
    bf16* __restrict__ q_h, bf16* __restrict__ k_h, bf16* __restrict__ vt_h,
    const bf16* __restrict__ cos_t, const bf16* __restrict__ sin_t) {
  // flattened grid 768 = 3 z * 8 n * 32 m ; bijective XCD swizzle (768 % 8 == 0)
  const int bid = blockIdx.x;
  const int swz = (bid & 7) * 96 + (bid >> 3);
  const int z = swz >> 8;            // 0..2
  const int rem = swz & 255;
  const int n0 = (rem >> 5) * 128;   // 8 n-tiles
  const int m0 = (rem & 31) * 128;   // 32 m-tiles

  const bf16* __restrict__ A  = z == 0 ? A0 : (z == 1 ? A1 : A2);
  const bf16* __restrict__ Bt = z == 0 ? Bt0 : (z == 1 ? Bt1 : Bt2);

  __shared__ bf16 As[2 * 128 * 32];   // 16 KiB (two 8 KiB buffers)
  __shared__ bf16 Bs[2 * 128 * 32];   // 16 KiB

  const int t = threadIdx.x;          // 0..255
  const int lane = t & 63;
  const int wid = t >> 6;             // 0..3
  const int quad = lane >> 4;
  const int l16 = lane & 15;
  const int wm = wid >> 1;            // 0..1 -> 64 rows each
  const int wn = wid & 1;             // 0..1 -> 64 cols each (one head per wave)

  // staging constants: linear LDS dest (wave-uniform base + lane*16B), pre-swizzled global source
  const int sc    = (t & 7) ^ ((t >> 3) & 7);   // c_orig for this lane's 16B chunk
  const int sml   = 2 * (t >> 3) + (sc >> 2);   // m row 0..63 (first issue); +64 second
  const int skoff = (sc & 3) * 8;               // k element offset
  const int swave = wid * 512;                  // wave-uniform LDS elem base (first issue)

  // fragment-read constants
  const int R0a = wm * 32 + (l16 >> 1);
  const int R0b = wn * 32 + (l16 >> 1);
  const int cpar = (l16 & 1) * 4;
  const int abase = R0a * 64 + (((cpar + quad) ^ (R0a & 7)) * 8);  // + mi*512 (+buf)
  const int bbase = R0b * 64 + (((cpar + quad) ^ (R0b & 7)) * 8);  // + ni*512 (+buf)

#define STAGE_A(KT, BUF) do { \
    const bf16* ag_ = A + (size_t)(m0 + sml) * nD + (KT) * 32 + skoff; \
    gload_lds16(ag_, As + (BUF) + swave); \
    gload_lds16(ag_ + (size_t)64 * nD, As + (BUF) + 2048 + swave); \
  } while (0)
#define STAGE_B(KT, BUF) do { \
    const bf16* bg_ = Bt + (size_t)(n0 + sml) * nD + (KT) * 32 + skoff; \
    gload_lds16(bg_, Bs + (BUF) + swave); \
    gload_lds16(bg_ + (size_t)64 * nD, Bs + (BUF) + 2048 + swave); \
  } while (0)

  float4v acc[4][4] = {};

  // prologue: tile 0 -> buf0
  STAGE_A(0, 0);
  STAGE_B(0, 0);
  asm volatile("s_waitcnt vmcnt(0)" ::: "memory");
  __builtin_amdgcn_s_barrier();

#pragma unroll 2
  for (int T = 0; T < 32; ++T) {
    const int cu = (T & 1) * 4096;
    const int nx = cu ^ 4096;

    if (T < 31) { STAGE_A(T + 1, nx); STAGE_B(T + 1, nx); }

    Frag16B fa[4], fb[4];
#pragma unroll
    for (int mi = 0; mi < 4; ++mi) fa[mi].u4 = *(const uint4*)&As[cu + abase + mi * 512];
#pragma unroll
    for (int ni = 0; ni < 4; ++ni) fb[ni].u4 = *(const uint4*)&Bs[cu + bbase + ni * 512];

    __builtin_amdgcn_s_setprio(1);
#pragma unroll
    for (int mi = 0; mi < 4; ++mi)
#pragma unroll
      for (int ni = 0; ni < 4; ++ni)
        acc[mi][ni] = __builtin_amdgcn_mfma_f32_16x16x32_bf16(fa[mi].v, fb[ni].v, acc[mi][ni], 0, 0, 0);
    __builtin_amdgcn_s_setprio(0);

    asm volatile("s_waitcnt vmcnt(0)" ::: "memory");
    __builtin_amdgcn_s_barrier();
  }
#undef STAGE_A
#undef STAGE_B

  // ---- epilogue: RoPE + RMSNorm (q,k) or transposed store (v)
  const int col0 = n0 + wn * 64;   // multiple of 64 -> one head per wave
  if (z <= 1) {
    bf16* dst = z ? k_h : q_h;
#pragma unroll
    for (int mi = 0; mi < 4; ++mi)
#pragma unroll
      for (int r = 0; r < 4; ++r) {
        int row = m0 + wm * 64 + mi * 16 + quad * 4 + r;
        int s = row & (nS - 1);
        float x0 = acc[mi][0][r], x1 = acc[mi][1][r], x2 = acc[mi][2][r], x3 = acc[mi][3][r];
        float y[4];
#pragma unroll
        for (int p = 0; p < 2; ++p) {
          int d = p * 16 + l16;
          float c = __bfloat162float(cos_t[s * 32 + d]);
          float sn = __bfloat162float(sin_t[s * 32 + d]);
          float xa = p ? x1 : x0, xb = p ? x3 : x2;
          y[p] = xa * c + xb * sn;
          y[p + 2] = xb * c - xa * sn;
        }
        float ss = y[0] * y[0] + y[1] * y[1] + y[2] * y[2] + y[3] * y[3];
#pragma unroll
        for (int m = 1; m <= 8; m <<= 1) ss += __shfl_xor(ss, m, 64);
        float inv = 1.0f / sqrtf(ss * (1.0f / 64.0f) + 1e-9f);
#pragma unroll
        for (int ni = 0; ni < 4; ++ni)
          dst[(size_t)row * nD + col0 + ni * 16 + l16] = __float2bfloat16(y[ni] * inv);
      }
  } else {
    // V: write transposed -> vt_h [b][h][d][s]
#pragma unroll
    for (int mi = 0; mi < 4; ++mi)
#pragma unroll
      for (int r = 0; r < 4; ++r) {
        int row = m0 + wm * 64 + mi * 16 + quad * 4 + r;
        int b = row >> 11, s = row & (nS - 1);
#pragma unroll
        for (int ni = 0; ni < 4; ++ni) {
          int col = col0 + ni * 16 + l16;
          int h = col >> 6, d = col & 63;
          vt_h[((size_t)((b * nH + h) * 64 + d)) * nS + s] = __float2bfloat16(acc[mi][ni][r]);
        }
      }
  }
}

// ---------------------------------------------------------------- output GEMM v2: 64x128 tile, BK=64,
// double-buffered 48 KiB LDS, ONE barrier per K-step. Grid 512 flattened, n-major (bid&7 = n-tile)
// so same-B-panel blocks land on the same XCD under round-robin dispatch.
__global__ __launch_bounds__(256, 2) void gemm_out_kernel(
    const bf16* __restrict__ A, const bf16* __restrict__ Bt, float* __restrict__ C) {
  __shared__ bf16 As[2 * 64 * 64];    // 16 KiB
  __shared__ bf16 Bs[2 * 128 * 64];   // 32 KiB
  const int bid = blockIdx.x;         // 0..511
  const int n0 = (bid & 7) * 128;
  const int m0 = (bid >> 3) * 64;
  const int t = threadIdx.x;
  const int lane = t & 63;
  const int wid = t >> 6;
  const int quad = lane >> 4;
  const int l16 = lane & 15;
  const int r7 = l16 & 7;
  const int wm = wid >> 1;
  const int wn = wid & 1;

  const int srow = t >> 3;                       // 0..31
  const int scg8 = ((t & 7) ^ (srow & 7)) * 8;

  const int ch0 = (quad ^ r7) * 8;
  const int ch1 = ch0 ^ 32;
  const int arow = (wm * 32 + l16) * 64;   // + mi*1024 (+buf)
  const int brow = (wn * 64 + l16) * 64;   // + ni*1024 (+buf)

#define STAGE_O(KT, AB, BB) do { \
    const bf16* ag_ = A + (size_t)(m0 + srow) * nD + (KT) * 64 + scg8; \
    const bf16* bg_ = Bt + (size_t)(n0 + srow) * nD + (KT) * 64 + scg8; \
    gload_lds16(ag_, As + (AB) + wid * 512); \
    gload_lds16(ag_ + (size_t)32 * nD, As + (AB) + 2048 + wid * 512); \
    _Pragma("unroll") \
    for (int i = 0; i < 4; ++i) \
      gload_lds16(bg_ + (size_t)(i * 32) * nD, Bs + (BB) + i * 2048 + wid * 512); \
  } while (0)

  float4v acc[2][4] = {};

  STAGE_O(0, 0, 0);
  asm volatile("s_waitcnt vmcnt(0)" ::: "memory");
  __builtin_amdgcn_s_barrier();

#pragma unroll 2
  for (int T = 0; T < 16; ++T) {
    const int cua = (T & 1) * 4096;
    const int cub = (T & 1) * 8192;

    if (T < 15) STAGE_O(T + 1, cua ^ 4096, cub ^ 8192);

    Frag16B a0[2], a1[2], b0[4], b1[4];
#pragma unroll
    for (int mi = 0; mi < 2; ++mi) {
      a0[mi].u4 = *(const uint4*)&As[cua + arow + mi * 1024 + ch0];
      a1[mi].u4 = *(const uint4*)&As[cua + arow + mi * 1024 + ch1];
    }
#pragma unroll
    for (int ni = 0; ni < 4; ++ni) {
      b0[ni].u4 = *(const uint4*)&Bs[cub + brow + ni * 1024 + ch0];
      b1[ni].u4 = *(const uint4*)&Bs[cub + brow + ni * 1024 + ch1];
    }

    __builtin_amdgcn_s_setprio(1);
#pragma unroll
    for (int mi = 0; mi < 2; ++mi)
#pragma unroll
      for (int ni = 0; ni < 4; ++ni)
        acc[mi][ni] = __builtin_amdgcn_mfma_f32_16x16x32_bf16(a0[mi].v, b0[ni].v, acc[mi][ni], 0, 0, 0);
#pragma unroll
    for (int mi = 0; mi < 2; ++mi)
#pragma unroll
      for (int ni = 0; ni < 4; ++ni)
        acc[mi][ni] = __builtin_amdgcn_mfma_f32_16x16x32_bf16(a1[mi].v, b1[ni].v, acc[mi][ni], 0, 0, 0);
    __builtin_amdgcn_s_setprio(0);

    asm volatile("s_waitcnt vmcnt(0)" ::: "memory");
    __builtin_amdgcn_s_barrier();
  }
#undef STAGE_O

#pragma unroll
  for (int mi = 0; mi < 2; ++mi)
#pragma unroll
    for (int ni = 0; ni < 4; ++ni)
#pragma unroll
      for (int r = 0; r < 4; ++r) {
        int row = m0 + wm * 32 + mi * 16 + quad * 4 + r;
        int col = n0 + wn * 64 + ni * 16 + l16;
        C[(size_t)row * nD + col] = acc[mi][ni][r];
      }
}

// ---------------------------------------------------------------- flash attention v8: KVBLK=128, 8-wave blocks,
// wave owns 16 q-rows. Main loop = full unmasked 128-key tiles (branchless); final diagonal tile
// handles all masking. K/V via global_load_lds, double-buffered 64 KiB LDS (2 blocks/CU),
// one vmcnt(0)+lgkm(0)+barrier per 128 keys.
static constexpr float SC = 0.18033688011112042f;  // 0.125 * log2(e)

__global__ __launch_bounds__(512, 4) void attn_kernel(const bf16* __restrict__ q_h,
                                                      const bf16* __restrict__ k_h,
                                                      const bf16* __restrict__ vt_h,
                                                      bf16* __restrict__ vals) {
  __shared__ bf16 lds_buf[4 * 8192];   // [K0|K1|V0|V1], 8192 elems each: K=128x64, V=2 half-subtiles 64x64

  const int t = threadIdx.x;           // 0..511
  const int lane = t & 63, wid = t >> 6, quad = lane >> 4, l16 = lane & 15;
  const int id = blockIdx.x;           // 0..511
  const int xcd = id & 7;              // round-robin XCD heuristic
  const int j = id >> 3;               // 0..63 per-XCD index
  const int jj = j & 31;
  const int bh = xcd * 4 + (jj & 3);   // 4 heads per XCD; pair blocks share bh
  const int u = jj >> 2;               // 0..7
  const int qt = (j < 32) ? (15 - u) : u;   // first CU-slot: long tiles; second: complementary short
  const int b = bh >> 4, h = bh & 15;

  const bf16* Kbase = k_h + ((size_t)b * nS) * nD + h * 64;
  const bf16* Vbase = vt_h + (size_t)bh * 64 * nS;  // [d][s]

  const int rl = lane >> 3;               // 0..7
  const int cg8 = ((lane & 7) ^ rl) * 8;  // pre-swizzled source chunk (elem offset)
  const int r7 = l16 & 7;

  bf16* const scratch = lds_buf + wid * 1152;  // 16 x 72 per wave (epilogue only)

  const int q0w = qt * 128 + wid * 16;         // wave's first q row

  // Q B-frags (col=q=l16, k=d), 2 d-halves
  Frag16B qf[2];
  {
    const bf16* qp = q_h + ((size_t)(b * nS + q0w + l16)) * nD + h * 64;
    qf[0].u4 = *(const uint4*)(qp + quad * 8);
    qf[1].u4 = *(const uint4*)(qp + 32 + quad * 8);
  }

  // stage 128-key K/V tile KT into buffer (KT&1): linear LDS dest, swizzled global source
#define STAGE_KV(KT) do { \
    const int bo_ = ((KT) & 1) * 8192; \
    const bf16* kg_ = Kbase + (size_t)((KT) * 128 + wid * 16 + rl) * nD + cg8; \
    gload_lds16(kg_, lds_buf + bo_ + wid * 1024); \
    gload_lds16(kg_ + (size_t)8 * nD, lds_buf + bo_ + wid * 1024 + 512); \
    const bf16* vg_ = Vbase + (size_t)(wid * 8 + rl) * nS + (KT) * 128 + cg8; \
    gload_lds16(vg_, lds_buf + 16384 + bo_ + wid * 512); \
    gload_lds16(vg_ + 64, lds_buf + 16384 + bo_ + 4096 + wid * 512); \
  } while (0)

  // QK^T for half HB of current K tile -> ST (S^T frags, key=row)
#define QKH(Kb, HB, ST) do { \
    _Pragma("unroll") \
    for (int kt4 = 0; kt4 < 4; ++kt4) { \
      int row = (HB) * 64 + kt4 * 16 + l16; \
      Frag16B k0_, k1_; \
      k0_.u4 = *(const uint4*)&(Kb)[row * 64 + ((quad ^ r7) * 8)]; \
      k1_.u4 = *(const uint4*)&(Kb)[row * 64 + (((quad + 4) ^ r7) * 8)]; \
      float4v zz_ = {}; \
      zz_ = __builtin_amdgcn_mfma_f32_16x16x32_bf16(k0_.v, qf[0].v, zz_, 0, 0, 0); \
      (ST)[kt4] = __builtin_amdgcn_mfma_f32_16x16x32_bf16(k1_.v, qf[1].v, zz_, 0, 0, 0); \
    } \
  } while (0)

  // exp (unmasked) ST -> PF, accumulate l_acc
#define EXPH(ST, PF) do { \
    _Pragma("unroll") \
    for (int kt4 = 0; kt4 < 4; ++kt4) \
      _Pragma("unroll") \
      for (int r = 0; r < 4; ++r) { \
        float p_ = fast_exp2((ST)[kt4][r] * SC); \
        l_acc += p_; \
        union { bf16 hh; short ss; } cv_; \
        cv_.hh = __float2bfloat16(p_); \
        (PF)[kt4][r] = cv_.ss; \
      } \
  } while (0)

  // exp (masked, diagonal tile) for half HB
#define EXPHM(ST, PF, HB) do { \
    int qg_ = q0w + l16; \
    _Pragma("unroll") \
    for (int kt4 = 0; kt4 < 4; ++kt4) { \
      int key0_ = qt * 128 + (HB) * 64 + kt4 * 16 + quad * 4; \
      _Pragma("unroll") \
      for (int r = 0; r < 4; ++r) { \
        float x_ = (ST)[kt4][r] * SC; \
        if (key0_ + r > qg_) x_ = -12000.0f; \
        float p_ = fast_exp2(x_); \
        l_acc += p_; \
        union { bf16 hh; short ss; } cv_; \
        cv_.hh = __float2bfloat16(p_); \
        (PF)[kt4][r] = cv_.ss; \
      } \
    } \
  } while (0)

  // O^T += V^T(half HB) . P^T
#define PVH(Vb, HB, PF) do { \
    _Pragma("unroll") \
    for (int dt = 0; dt < 4; ++dt) { \
      int row = dt * 16 + l16; \
      _Pragma("unroll") \
      for (int kt4 = 0; kt4 < 4; ++kt4) { \
        int chunk_ = kt4 * 2 + (quad >> 1); \
        union { uint2 u; short4v s; } vv_; \
        vv_.u = *(const uint2*)&(Vb)[(HB) * 4096 + row * 64 + ((chunk_ ^ r7) * 8) + (quad & 1) * 4]; \
        o_acc[dt] = __builtin_amdgcn_mfma_f32_16x16x16bf16_1k(vv_.s, (PF)[kt4], o_acc[dt], 0, 0, 0); \
      } \
    } \
  } while (0)

  STAGE_KV(0);
  asm volatile("s_waitcnt vmcnt(0)" ::: "memory");
  __builtin_amdgcn_s_barrier();

  float4v o_acc[4] = {};
  float l_acc = 0.f;

  // ---- main loop: full unmasked tiles (branchless)
  for (int kt = 0; kt < qt; ++kt) {
    STAGE_KV(kt + 1);
    const bf16* Kb = lds_buf + (kt & 1) * 8192;
    const bf16* Vb = lds_buf + 16384 + (kt & 1) * 8192;

    float4v st0[4], st1[4];
    __builtin_amdgcn_s_setprio(1);
    QKH(Kb, 0, st0);
    QKH(Kb, 1, st1);
    __builtin_amdgcn_s_setprio(0);

    short4v pf[4];
    EXPH(st0, pf);
    __builtin_amdgcn_s_setprio(1);
    PVH(Vb, 0, pf);
    __builtin_amdgcn_s_setprio(0);
    EXPH(st1, pf);
    __builtin_amdgcn_s_setprio(1);
    PVH(Vb, 1, pf);
    __builtin_amdgcn_s_setprio(0);

    asm volatile("s_waitcnt vmcnt(0) lgkmcnt(0)" ::: "memory");
    __builtin_amdgcn_s_barrier();
  }

  // ---- final diagonal tile kt = qt (no prefetch; all masking lives here)
  {
    const bf16* Kb = lds_buf + (qt & 1) * 8192;
    const bf16* Vb = lds_buf + 16384 + (qt & 1) * 8192;

    float4v st0[4];
    QKH(Kb, 0, st0);
    short4v pf[4];
    EXPHM(st0, pf, 0);
    PVH(Vb, 0, pf);

    if (wid >= 4) {   // waves 0-3: h1 keys are all > q0w+15 (fully masked) -> skip
      float4v st1[4];
      QKH(Kb, 1, st1);
      EXPHM(st1, pf, 1);
      PVH(Vb, 1, pf);
    }
  }
#undef STAGE_KV
#undef QKH
#undef EXPH
#undef EXPHM
#undef PVH

  // all waves done reading K/V before scratch (overlapping K region) is overwritten
  lds_barrier();

  // ---- epilogue: row-sum reduce, LDS-transpose, coalesced 16B stores
  float la = l_acc;
  la += __shfl_xor(la, 16, 64);
  la += __shfl_xor(la, 32, 64);
  float inv_l = 1.0f / la;
  // write transposed: scratch[q_loc=l16][d]
#pragma unroll
  for (int dt = 0; dt < 4; ++dt) {
    union { bf16 b2[2]; uint u; } p01, p23;
    p01.b2[0] = __float2bfloat16(o_acc[dt][0] * inv_l);
    p01.b2[1] = __float2bfloat16(o_acc[dt][1] * inv_l);
    p23.b2[0] = __float2bfloat16(o_acc[dt][2] * inv_l);
    p23.b2[1] = __float2bfloat16(o_acc[dt][3] * inv_l);
    *(uint*)&scratch[l16 * 72 + dt * 16 + quad * 4] = p01.u;
    *(uint*)&scratch[l16 * 72 + dt * 16 + quad * 4 + 2] = p23.u;
  }
  lgkm_wait();  // own writes visible to own reads
  uint4 r0 = *(const uint4*)&scratch[l16 * 72 + quad * 16];
  uint4 r1 = *(const uint4*)&scratch[l16 * 72 + quad * 16 + 8];
  int qrow = q0w + l16;
  bf16* vp = vals + ((size_t)(b * nS + qrow)) * nD + h * 64 + quad * 16;
  *(uint4*)(vp) = r0;
  *(uint4*)(vp + 8) = r1;
}

// ---------------------------------------------------------------- launch
extern "C" void kernel_launch(void* const* d_in, const int* in_sizes, int n_in,
                              void* d_out, int out_size, void* d_ws, size_t ws_size,
                              hipStream_t stream) {
  const float* Qin = (const float*)d_in[0];
  const float* Kin = (const float*)d_in[1];
  const float* Vin = (const float*)d_in[2];
  const float* Wq = (const float*)d_in[4];
  const float* Wk = (const float*)d_in[5];
  const float* Wv = (const float*)d_in[6];
  const float* Wo = (const float*)d_in[7];
  float* out = (float*)d_out;

  char* ws = (char*)d_ws;
  const size_t MB = 1u << 20;
  bf16* Qbf = (bf16*)(ws + 0 * MB);
  bf16* Kbf = (bf16*)(ws + 8 * MB);
  bf16* Vbf = (bf16*)(ws + 16 * MB);
  bf16* WqT = (bf16*)(ws + 24 * MB);
  bf16* WkT = (bf16*)(ws + 26 * MB);
  bf16* WvT = (bf16*)(ws + 28 * MB);
  bf16* WoT = (bf16*)(ws + 30 * MB);
  bf16* cos_t = (bf16*)(ws + 32 * MB);
  bf16* sin_t = (bf16*)(ws + 33 * MB);
  bf16* q_h = (bf16*)(ws + 34 * MB);
  bf16* k_h = (bf16*)(ws + 42 * MB);
  bf16* vt_h = (bf16*)(ws + 50 * MB);
  bf16* vals = (bf16*)(ws + 58 * MB);

  prep_kernel<<<4160, 256, 0, stream>>>(Qin, Kin, Vin, Wq, Wk, Wv, Wo,
                                        Qbf, Kbf, Vbf, WqT, WkT, WvT, WoT, cos_t, sin_t);

  gemm_qkv_kernel<<<768, 256, 0, stream>>>(Qbf, Kbf, Vbf, WqT, WkT, WvT,
                                           q_h, k_h, vt_h, cos_t, sin_t);

  attn_kernel<<<512, 512, 0, stream>>>(q_h, k_h, vt_h, vals);

  gemm_out_kernel<<<512, 256, 0, stream>>>(vals, WoT, out);
}

// Round 9
// 210.224 us; speedup vs baseline: 1.0302x; 1.0205x over previous
//
#include <hip/hip_runtime.h>
#include <hip/hip_bf16.h>
#include <stdint.h>

typedef __hip_bfloat16 bf16;
typedef __attribute__((ext_vector_type(8))) short short8;
typedef __attribute__((ext_vector_type(4))) short short4v;
typedef __attribute__((ext_vector_type(4))) float float4v;

static constexpr int nB = 2, nS = 2048, nD = 1024, nH = 16, nHD = 64;
static constexpr int nBS = nB * nS;   // 4096

#define AS_GLOBAL __attribute__((address_space(1)))
#define AS_LDS    __attribute__((address_space(3)))

union Frag16B { short8 v; uint4 u4; uint2 u2[2]; };

__device__ __forceinline__ void gload_lds16(const void* g, void* l) {
  __builtin_amdgcn_global_load_lds((AS_GLOBAL uint32_t*)(g), (AS_LDS uint32_t*)(l), 16, 0, 0);
}

__device__ __forceinline__ float fast_exp2(float x) {
#if __has_builtin(__builtin_amdgcn_exp2f)
  return __builtin_amdgcn_exp2f(x);
#else
  float r; asm volatile("v_exp_f32 %0, %1" : "=v"(r) : "v"(x)); return r;
#endif
}

// drain LDS ops but NOT vmem: prefetch global loads stay in flight across the barrier
__device__ __forceinline__ void lds_barrier() {
  asm volatile("s_waitcnt lgkmcnt(0)\ns_barrier" ::: "memory");
}

__device__ __forceinline__ void lgkm_wait() {
  asm volatile("s_waitcnt lgkmcnt(0)" ::: "memory");
}

// ---------------------------------------------------------------- prep: cast QKV->bf16, W->W^T bf16, rope tables
__global__ __launch_bounds__(256) void prep_kernel(
    const float* __restrict__ Qin, const float* __restrict__ Kin, const float* __restrict__ Vin,
    const float* __restrict__ Wq, const float* __restrict__ Wk,
    const float* __restrict__ Wv, const float* __restrict__ Wo,
    bf16* __restrict__ Qbf, bf16* __restrict__ Kbf, bf16* __restrict__ Vbf,
    bf16* __restrict__ WqT, bf16* __restrict__ WkT, bf16* __restrict__ WvT, bf16* __restrict__ WoT,
    bf16* __restrict__ cos_t, bf16* __restrict__ sin_t) {
  __shared__ float tile[64][65];
  int bx = blockIdx.x, t = threadIdx.x;
  if (bx < 3072) {
    int tz = bx >> 10, blk = bx & 1023;
    const float* src = tz == 0 ? Qin : tz == 1 ? Kin : Vin;
    bf16* dst = tz == 0 ? Qbf : tz == 1 ? Kbf : Vbf;
#pragma unroll
    for (int i = 0; i < 4; ++i) {
      int idx = blk * 1024 + i * 256 + t;  // float4 index
      float4 v = ((const float4*)src)[idx];
      union { bf16 b[4]; uint2 u; } tmp;
      tmp.b[0] = __float2bfloat16(v.x);
      tmp.b[1] = __float2bfloat16(v.y);
      tmp.b[2] = __float2bfloat16(v.z);
      tmp.b[3] = __float2bfloat16(v.w);
      ((uint2*)dst)[idx] = tmp.u;
    }
  } else if (bx < 4096) {
    int idx = bx - 3072;
    int z = idx >> 8;
    const float* W = z == 0 ? Wq : z == 1 ? Wk : z == 2 ? Wv : Wo;
    bf16* T = z == 0 ? WqT : z == 1 ? WkT : z == 2 ? WvT : WoT;
    int tk = (idx & 15) * 64, tn = ((idx >> 4) & 15) * 64;
    int c = t & 63, r0 = t >> 6;
#pragma unroll
    for (int i = 0; i < 16; ++i) {
      int r = i * 4 + r0;
      tile[r][c] = W[(size_t)(tk + r) * nD + tn + c];
    }
    __syncthreads();
#pragma unroll
    for (int i = 0; i < 16; ++i) {
      int r = i * 4 + r0;
      T[(size_t)(tn + r) * nD + tk + c] = __float2bfloat16(tile[c][r]);
    }
  } else {
    int base = (bx - 4096) * 1024 + t * 4;
#pragma unroll
    for (int i = 0; i < 4; ++i) {
      int e = base + i;
      int s = e >> 5, j = e & 31;
      float inv_freq = powf(100000.0f, -(float)(2 * j) / 64.0f);
      float g = (float)s * inv_freq;
      cos_t[e] = __float2bfloat16(cosf(g));
      sin_t[e] = __float2bfloat16(sinf(g));
    }
  }
}

// ---------------------------------------------------------------- fused projection GEMM v5: m97-faithful.
// 128x128 tile, BK=64, 4 waves (2Mx2N, each 64x64), SINGLE-buffered 32 KiB LDS, 2 barriers/K-step:
//   step T: stage tile T (8 x gload_lds16) | vmcnt(0) | barrier | 16 ds_read_b128 + 32 MFMA | barrier
// Latency hiding comes from cross-block TLP (3 blocks/CU at 32 KiB; m114: implicit wave-level overlap
// ≈ explicit pipelining). LDS row R = 64 k, chunk c stored at c ^ (R&7); staging reads pre-swizzled
// global chunk (t&7)^(R&7) into linear LDS chunk (t&7). Grid 768 flattened, bijective XCD swizzle.
__global__ __launch_bounds__(256, 3) void gemm_qkv_kernel(
    const bf16* __restrict__ A0, const bf16* __restrict__ A1, const bf16* __restrict__ A2,
    const bf16* __restrict__ Bt0, const bf16* __restrict__ Bt1, const bf16* __restrict__ Bt2,
    bf16* __restrict__ q_h, bf16* __restrict__ k_h, bf16* __restrict__ vt_h,
    const bf16* __restrict__ cos_t, const bf16* __restrict__ sin_t) {
  // flattened grid 768 = 3 z * 8 n * 32 m ; bijective XCD swizzle (768 % 8 == 0)
  const int bid = blockIdx.x;
  const int swz = (bid & 7) * 96 + (bid >> 3);
  const int z = swz >> 8;            // 0..2
  const int rem = swz & 255;
  const int n0 = (rem >> 5) * 128;   // 8 n-tiles
  const int m0 = (rem & 31) * 128;   // 32 m-tiles

  const bf16* __restrict__ A  = z == 0 ? A0 : (z == 1 ? A1 : A2);
  const bf16* __restrict__ Bt = z == 0 ? Bt0 : (z == 1 ? Bt1 : Bt2);

  __shared__ bf16 As[128 * 64];   // 16 KiB
  __shared__ bf16 Bs[128 * 64];   // 16 KiB

  const int t = threadIdx.x;          // 0..255
  const int lane = t & 63;
  const int wid = t >> 6;             // 0..3
  const int quad = lane >> 4;
  const int l16 = lane & 15;
  const int r7 = l16 & 7;
  const int wm = wid >> 1;            // 0..1 -> 64 rows each
  const int wn = wid & 1;             // 0..1 -> 64 cols each (one head per wave)

  // staging: issue i covers rows i*32 + (t>>3); linear LDS dest, pre-swizzled global source
  const int srow = t >> 3;                       // 0..31
  const int scg8 = ((t & 7) ^ (srow & 7)) * 8;   // swizzled k-offset (elements)

  // fragment-read offsets: row = {wm|wn}*64 + mi*16 + l16, chunk = (kk*4+quad) ^ r7
  const int ch0 = (quad ^ r7) * 8;
  const int ch1 = ch0 ^ 32;
  const int arow = (wm * 64 + l16) * 64;   // + mi*1024
  const int brow = (wn * 64 + l16) * 64;   // + ni*1024

  float4v acc[4][4] = {};

  for (int T = 0; T < 16; ++T) {
    // ---- stage tile T into the (single) buffer
    {
      const bf16* ag_ = A + (size_t)(m0 + srow) * nD + T * 64 + scg8;
      const bf16* bg_ = Bt + (size_t)(n0 + srow) * nD + T * 64 + scg8;
#pragma unroll
      for (int i = 0; i < 4; ++i) {
        gload_lds16(ag_ + (size_t)(i * 32) * nD, As + i * 2048 + wid * 512);
        gload_lds16(bg_ + (size_t)(i * 32) * nD, Bs + i * 2048 + wid * 512);
      }
    }
    asm volatile("s_waitcnt vmcnt(0)" ::: "memory");
    __builtin_amdgcn_s_barrier();

    // ---- compute BK=64 from LDS
    Frag16B fa0[4], fa1[4], fb0[4], fb1[4];
#pragma unroll
    for (int mi = 0; mi < 4; ++mi) {
      fa0[mi].u4 = *(const uint4*)&As[arow + mi * 1024 + ch0];
      fa1[mi].u4 = *(const uint4*)&As[arow + mi * 1024 + ch1];
    }
#pragma unroll
    for (int ni = 0; ni < 4; ++ni) {
      fb0[ni].u4 = *(const uint4*)&Bs[brow + ni * 1024 + ch0];
      fb1[ni].u4 = *(const uint4*)&Bs[brow + ni * 1024 + ch1];
    }

    __builtin_amdgcn_s_setprio(1);
#pragma unroll
    for (int mi = 0; mi < 4; ++mi)
#pragma unroll
      for (int ni = 0; ni < 4; ++ni)
        acc[mi][ni] = __builtin_amdgcn_mfma_f32_16x16x32_bf16(fa0[mi].v, fb0[ni].v, acc[mi][ni], 0, 0, 0);
#pragma unroll
    for (int mi = 0; mi < 4; ++mi)
#pragma unroll
      for (int ni = 0; ni < 4; ++ni)
        acc[mi][ni] = __builtin_amdgcn_mfma_f32_16x16x32_bf16(fa1[mi].v, fb1[ni].v, acc[mi][ni], 0, 0, 0);
    __builtin_amdgcn_s_setprio(0);

    __builtin_amdgcn_s_barrier();   // all waves done reading before next T's stage overwrites
  }

  // ---- epilogue: RoPE + RMSNorm (q,k) or transposed store (v)
  const int col0 = n0 + wn * 64;   // multiple of 64 -> one head per wave
  if (z <= 1) {
    bf16* dst = z ? k_h : q_h;
#pragma unroll
    for (int mi = 0; mi < 4; ++mi)
#pragma unroll
      for (int r = 0; r < 4; ++r) {
        int row = m0 + wm * 64 + mi * 16 + quad * 4 + r;
        int s = row & (nS - 1);
        float x0 = acc[mi][0][r], x1 = acc[mi][1][r], x2 = acc[mi][2][r], x3 = acc[mi][3][r];
        float y[4];
#pragma unroll
        for (int p = 0; p < 2; ++p) {
          int d = p * 16 + l16;
          float c = __bfloat162float(cos_t[s * 32 + d]);
          float sn = __bfloat162float(sin_t[s * 32 + d]);
          float xa = p ? x1 : x0, xb = p ? x3 : x2;
          y[p] = xa * c + xb * sn;
          y[p + 2] = xb * c - xa * sn;
        }
        float ss = y[0] * y[0] + y[1] * y[1] + y[2] * y[2] + y[3] * y[3];
#pragma unroll
        for (int m = 1; m <= 8; m <<= 1) ss += __shfl_xor(ss, m, 64);
        float inv = 1.0f / sqrtf(ss * (1.0f / 64.0f) + 1e-9f);
#pragma unroll
        for (int ni = 0; ni < 4; ++ni)
          dst[(size_t)row * nD + col0 + ni * 16 + l16] = __float2bfloat16(y[ni] * inv);
      }
  } else {
    // V: write transposed -> vt_h [b][h][d][s]
#pragma unroll
    for (int mi = 0; mi < 4; ++mi)
#pragma unroll
      for (int r = 0; r < 4; ++r) {
        int row = m0 + wm * 64 + mi * 16 + quad * 4 + r;
        int b = row >> 11, s = row & (nS - 1);
#pragma unroll
        for (int ni = 0; ni < 4; ++ni) {
          int col = col0 + ni * 16 + l16;
          int h = col >> 6, d = col & 63;
          vt_h[((size_t)((b * nH + h) * 64 + d)) * nS + s] = __float2bfloat16(acc[mi][ni][r]);
        }
      }
  }
}

// ---------------------------------------------------------------- output GEMM v2: 64x128 tile, BK=64,
// double-buffered 48 KiB LDS, ONE barrier per K-step. Grid 512 flattened, n-major (bid&7 = n-tile)
// so same-B-panel blocks land on the same XCD under round-robin dispatch.
__global__ __launch_bounds__(256, 2) void gemm_out_kernel(
    const bf16* __restrict__ A, const bf16* __restrict__ Bt, float* __restrict__ C) {
  __shared__ bf16 As[2 * 64 * 64];    // 16 KiB
  __shared__ bf16 Bs[2 * 128 * 64];   // 32 KiB
  const int bid = blockIdx.x;         // 0..511
  const int n0 = (bid & 7) * 128;
  const int m0 = (bid >> 3) * 64;
  const int t = threadIdx.x;
  const int lane = t & 63;
  const int wid = t >> 6;
  const int quad = lane >> 4;
  const int l16 = lane & 15;
  const int r7 = l16 & 7;
  const int wm = wid >> 1;
  const int wn = wid & 1;

  const int srow = t >> 3;                       // 0..31
  const int scg8 = ((t & 7) ^ (srow & 7)) * 8;

  const int ch0 = (quad ^ r7) * 8;
  const int ch1 = ch0 ^ 32;
  const int arow = (wm * 32 + l16) * 64;   // + mi*1024 (+buf)
  const int brow = (wn * 64 + l16) * 64;   // + ni*1024 (+buf)

#define STAGE_O(KT, AB, BB) do { \
    const bf16* ag_ = A + (size_t)(m0 + srow) * nD + (KT) * 64 + scg8; \
    const bf16* bg_ = Bt + (size_t)(n0 + srow) * nD + (KT) * 64 + scg8; \
    gload_lds16(ag_, As + (AB) + wid * 512); \
    gload_lds16(ag_ + (size_t)32 * nD, As + (AB) + 2048 + wid * 512); \
    _Pragma("unroll") \
    for (int i = 0; i < 4; ++i) \
      gload_lds16(bg_ + (size_t)(i * 32) * nD, Bs + (BB) + i * 2048 + wid * 512); \
  } while (0)

  float4v acc[2][4] = {};

  STAGE_O(0, 0, 0);
  asm volatile("s_waitcnt vmcnt(0)" ::: "memory");
  __builtin_amdgcn_s_barrier();

#pragma unroll 2
  for (int T = 0; T < 16; ++T) {
    const int cua = (T & 1) * 4096;
    const int cub = (T & 1) * 8192;

    if (T < 15) STAGE_O(T + 1, cua ^ 4096, cub ^ 8192);

    Frag16B a0[2], a1[2], b0[4], b1[4];
#pragma unroll
    for (int mi = 0; mi < 2; ++mi) {
      a0[mi].u4 = *(const uint4*)&As[cua + arow + mi * 1024 + ch0];
      a1[mi].u4 = *(const uint4*)&As[cua + arow + mi * 1024 + ch1];
    }
#pragma unroll
    for (int ni = 0; ni < 4; ++ni) {
      b0[ni].u4 = *(const uint4*)&Bs[cub + brow + ni * 1024 + ch0];
      b1[ni].u4 = *(const uint4*)&Bs[cub + brow + ni * 1024 + ch1];
    }

    __builtin_amdgcn_s_setprio(1);
#pragma unroll
    for (int mi = 0; mi < 2; ++mi)
#pragma unroll
      for (int ni = 0; ni < 4; ++ni)
        acc[mi][ni] = __builtin_amdgcn_mfma_f32_16x16x32_bf16(a0[mi].v, b0[ni].v, acc[mi][ni], 0, 0, 0);
#pragma unroll
    for (int mi = 0; mi < 2; ++mi)
#pragma unroll
      for (int ni = 0; ni < 4; ++ni)
        acc[mi][ni] = __builtin_amdgcn_mfma_f32_16x16x32_bf16(a1[mi].v, b1[ni].v, acc[mi][ni], 0, 0, 0);
    __builtin_amdgcn_s_setprio(0);

    asm volatile("s_waitcnt vmcnt(0)" ::: "memory");
    __builtin_amdgcn_s_barrier();
  }
#undef STAGE_O

#pragma unroll
  for (int mi = 0; mi < 2; ++mi)
#pragma unroll
    for (int ni = 0; ni < 4; ++ni)
#pragma unroll
      for (int r = 0; r < 4; ++r) {
        int row = m0 + wm * 32 + mi * 16 + quad * 4 + r;
        int col = n0 + wn * 64 + ni * 16 + l16;
        C[(size_t)row * nD + col] = acc[mi][ni][r];
      }
}

// ---------------------------------------------------------------- flash attention v8: KVBLK=128, 8-wave blocks,
// wave owns 16 q-rows. Main loop = full unmasked 128-key tiles (branchless); final diagonal tile
// handles all masking. K/V via global_load_lds, double-buffered 64 KiB LDS (2 blocks/CU),
// one vmcnt(0)+lgkm(0)+barrier per 128 keys.
static constexpr float SC = 0.18033688011112042f;  // 0.125 * log2(e)

__global__ __launch_bounds__(512, 4) void attn_kernel(const bf16* __restrict__ q_h,
                                                      const bf16* __restrict__ k_h,
                                                      const bf16* __restrict__ vt_h,
                                                      bf16* __restrict__ vals) {
  __shared__ bf16 lds_buf[4 * 8192];   // [K0|K1|V0|V1], 8192 elems each: K=128x64, V=2 half-subtiles 64x64

  const int t = threadIdx.x;           // 0..511
  const int lane = t & 63, wid = t >> 6, quad = lane >> 4, l16 = lane & 15;
  const int id = blockIdx.x;           // 0..511
  const int xcd = id & 7;              // round-robin XCD heuristic
  const int j = id >> 3;               // 0..63 per-XCD index
  const int jj = j & 31;
  const int bh = xcd * 4 + (jj & 3);   // 4 heads per XCD; pair blocks share bh
  const int u = jj >> 2;               // 0..7
  const int qt = (j < 32) ? (15 - u) : u;   // first CU-slot: long tiles; second: complementary short
  const int b = bh >> 4, h = bh & 15;

  const bf16* Kbase = k_h + ((size_t)b * nS) * nD + h * 64;
  const bf16* Vbase = vt_h + (size_t)bh * 64 * nS;  // [d][s]

  const int rl = lane >> 3;               // 0..7
  const int cg8 = ((lane & 7) ^ rl) * 8;  // pre-swizzled source chunk (elem offset)
  const int r7 = l16 & 7;

  bf16* const scratch = lds_buf + wid * 1152;  // 16 x 72 per wave (epilogue only)

  const int q0w = qt * 128 + wid * 16;         // wave's first q row

  // Q B-frags (col=q=l16, k=d), 2 d-halves
  Frag16B qf[2];
  {
    const bf16* qp = q_h + ((size_t)(b * nS + q0w + l16)) * nD + h * 64;
    qf[0].u4 = *(const uint4*)(qp + quad * 8);
    qf[1].u4 = *(const uint4*)(qp + 32 + quad * 8);
  }

  // stage 128-key K/V tile KT into buffer (KT&1): linear LDS dest, swizzled global source
#define STAGE_KV(KT) do { \
    const int bo_ = ((KT) & 1) * 8192; \
    const bf16* kg_ = Kbase + (size_t)((KT) * 128 + wid * 16 + rl) * nD + cg8; \
    gload_lds16(kg_, lds_buf + bo_ + wid * 1024); \
    gload_lds16(kg_ + (size_t)8 * nD, lds_buf + bo_ + wid * 1024 + 512); \
    const bf16* vg_ = Vbase + (size_t)(wid * 8 + rl) * nS + (KT) * 128 + cg8; \
    gload_lds16(vg_, lds_buf + 16384 + bo_ + wid * 512); \
    gload_lds16(vg_ + 64, lds_buf + 16384 + bo_ + 4096 + wid * 512); \
  } while (0)

  // QK^T for half HB of current K tile -> ST (S^T frags, key=row)
#define QKH(Kb, HB, ST) do { \
    _Pragma("unroll") \
    for (int kt4 = 0; kt4 < 4; ++kt4) { \
      int row = (HB) * 64 + kt4 * 16 + l16; \
      Frag16B k0_, k1_; \
      k0_.u4 = *(const uint4*)&(Kb)[row * 64 + ((quad ^ r7) * 8)]; \
      k1_.u4 = *(const uint4*)&(Kb)[row * 64 + (((quad + 4) ^ r7) * 8)]; \
      float4v zz_ = {}; \
      zz_ = __builtin_amdgcn_mfma_f32_16x16x32_bf16(k0_.v, qf[0].v, zz_, 0, 0, 0); \
      (ST)[kt4] = __builtin_amdgcn_mfma_f32_16x16x32_bf16(k1_.v, qf[1].v, zz_, 0, 0, 0); \
    } \
  } while (0)

  // exp (unmasked) ST -> PF, accumulate l_acc
#define EXPH(ST, PF) do { \
    _Pragma("unroll") \
    for (int kt4 = 0; kt4 < 4; ++kt4) \
      _Pragma("unroll") \
      for (int r = 0; r < 4; ++r) { \
        float p_ = fast_exp2((ST)[kt4][r] * SC); \
        l_acc += p_; \
        union { bf16 hh; short ss; } cv_; \
        cv_.hh = __float2bfloat16(p_); \
        (PF)[kt4][r] = cv_.ss; \
      } \
  } while (0)

  // exp (masked, diagonal tile) for half HB
#define EXPHM(ST, PF, HB) do { \
    int qg_ = q0w + l16; \
    _Pragma("unroll") \
    for (int kt4 = 0; kt4 < 4; ++kt4) { \
      int key0_ = qt * 128 + (HB) * 64 + kt4 * 16 + quad * 4; \
      _Pragma("unroll") \
      for (int r = 0; r < 4; ++r) { \
        float x_ = (ST)[kt4][r] * SC; \
        if (key0_ + r > qg_) x_ = -12000.0f; \
        float p_ = fast_exp2(x_); \
        l_acc += p_; \
        union { bf16 hh; short ss; } cv_; \
        cv_.hh = __float2bfloat16(p_); \
        (PF)[kt4][r] = cv_.ss; \
      } \
    } \
  } while (0)

  // O^T += V^T(half HB) . P^T
#define PVH(Vb, HB, PF) do { \
    _Pragma("unroll") \
    for (int dt = 0; dt < 4; ++dt) { \
      int row = dt * 16 + l16; \
      _Pragma("unroll") \
      for (int kt4 = 0; kt4 < 4; ++kt4) { \
        int chunk_ = kt4 * 2 + (quad >> 1); \
        union { uint2 u; short4v s; } vv_; \
        vv_.u = *(const uint2*)&(Vb)[(HB) * 4096 + row * 64 + ((chunk_ ^ r7) * 8) + (quad & 1) * 4]; \
        o_acc[dt] = __builtin_amdgcn_mfma_f32_16x16x16bf16_1k(vv_.s, (PF)[kt4], o_acc[dt], 0, 0, 0); \
      } \
    } \
  } while (0)

  STAGE_KV(0);
  asm volatile("s_waitcnt vmcnt(0)" ::: "memory");
  __builtin_amdgcn_s_barrier();

  float4v o_acc[4] = {};
  float l_acc = 0.f;

  // ---- main loop: full unmasked tiles (branchless)
  for (int kt = 0; kt < qt; ++kt) {
    STAGE_KV(kt + 1);
    const bf16* Kb = lds_buf + (kt & 1) * 8192;
    const bf16* Vb = lds_buf + 16384 + (kt & 1) * 8192;

    float4v st0[4], st1[4];
    __builtin_amdgcn_s_setprio(1);
    QKH(Kb, 0, st0);
    QKH(Kb, 1, st1);
    __builtin_amdgcn_s_setprio(0);

    short4v pf[4];
    EXPH(st0, pf);
    __builtin_amdgcn_s_setprio(1);
    PVH(Vb, 0, pf);
    __builtin_amdgcn_s_setprio(0);
    EXPH(st1, pf);
    __builtin_amdgcn_s_setprio(1);
    PVH(Vb, 1, pf);
    __builtin_amdgcn_s_setprio(0);

    asm volatile("s_waitcnt vmcnt(0) lgkmcnt(0)" ::: "memory");
    __builtin_amdgcn_s_barrier();
  }

  // ---- final diagonal tile kt = qt (no prefetch; all masking lives here)
  {
    const bf16* Kb = lds_buf + (qt & 1) * 8192;
    const bf16* Vb = lds_buf + 16384 + (qt & 1) * 8192;

    float4v st0[4];
    QKH(Kb, 0, st0);
    short4v pf[4];
    EXPHM(st0, pf, 0);
    PVH(Vb, 0, pf);

    if (wid >= 4) {   // waves 0-3: h1 keys are all > q0w+15 (fully masked) -> skip
      float4v st1[4];
      QKH(Kb, 1, st1);
      EXPHM(st1, pf, 1);
      PVH(Vb, 1, pf);
    }
  }
#undef STAGE_KV
#undef QKH
#undef EXPH
#undef EXPHM
#undef PVH

  // all waves done reading K/V before scratch (overlapping K region) is overwritten
  lds_barrier();

  // ---- epilogue: row-sum reduce, LDS-transpose, coalesced 16B stores
  float la = l_acc;
  la += __shfl_xor(la, 16, 64);
  la += __shfl_xor(la, 32, 64);
  float inv_l = 1.0f / la;
  // write transposed: scratch[q_loc=l16][d]
#pragma unroll
  for (int dt = 0; dt < 4; ++dt) {
    union { bf16 b2[2]; uint u; } p01, p23;
    p01.b2[0] = __float2bfloat16(o_acc[dt][0] * inv_l);
    p01.b2[1] = __float2bfloat16(o_acc[dt][1] * inv_l);
    p23.b2[0] = __float2bfloat16(o_acc[dt][2] * inv_l);
    p23.b2[1] = __float2bfloat16(o_acc[dt][3] * inv_l);
    *(uint*)&scratch[l16 * 72 + dt * 16 + quad * 4] = p01.u;
    *(uint*)&scratch[l16 * 72 + dt * 16 + quad * 4 + 2] = p23.u;
  }
  lgkm_wait();  // own writes visible to own reads
  uint4 r0 = *(const uint4*)&scratch[l16 * 72 + quad * 16];
  uint4 r1 = *(const uint4*)&scratch[l16 * 72 + quad * 16 + 8];
  int qrow = q0w + l16;
  bf16* vp = vals + ((size_t)(b * nS + qrow)) * nD + h * 64 + quad * 16;
  *(uint4*)(vp) = r0;
  *(uint4*)(vp + 8) = r1;
}

// ---------------------------------------------------------------- launch
extern "C" void kernel_launch(void* const* d_in, const int* in_sizes, int n_in,
                              void* d_out, int out_size, void* d_ws, size_t ws_size,
                              hipStream_t stream) {
  const float* Qin = (const float*)d_in[0];
  const float* Kin = (const float*)d_in[1];
  const float* Vin = (const float*)d_in[2];
  const float* Wq = (const float*)d_in[4];
  const float* Wk = (const float*)d_in[5];
  const float* Wv = (const float*)d_in[6];
  const float* Wo = (const float*)d_in[7];
  float* out = (float*)d_out;

  char* ws = (char*)d_ws;
  const size_t MB = 1u << 20;
  bf16* Qbf = (bf16*)(ws + 0 * MB);
  bf16* Kbf = (bf16*)(ws + 8 * MB);
  bf16* Vbf = (bf16*)(ws + 16 * MB);
  bf16* WqT = (bf16*)(ws + 24 * MB);
  bf16* WkT = (bf16*)(ws + 26 * MB);
  bf16* WvT = (bf16*)(ws + 28 * MB);
  bf16* WoT = (bf16*)(ws + 30 * MB);
  bf16* cos_t = (bf16*)(ws + 32 * MB);
  bf16* sin_t = (bf16*)(ws + 33 * MB);
  bf16* q_h = (bf16*)(ws + 34 * MB);
  bf16* k_h = (bf16*)(ws + 42 * MB);
  bf16* vt_h = (bf16*)(ws + 50 * MB);
  bf16* vals = (bf16*)(ws + 58 * MB);

  prep_kernel<<<4160, 256, 0, stream>>>(Qin, Kin, Vin, Wq, Wk, Wv, Wo,
                                        Qbf, Kbf, Vbf, WqT, WkT, WvT, WoT, cos_t, sin_t);

  gemm_qkv_kernel<<<768, 256, 0, stream>>>(Qbf, Kbf, Vbf, WqT, WkT, WvT,
                                           q_h, k_h, vt_h, cos_t, sin_t);

  attn_kernel<<<512, 512, 0, stream>>>(q_h, k_h, vt_h, vals);

  gemm_out_kernel<<<512, 256, 0, stream>>>(vals, WoT, out);
}

// Round 12
// 208.975 us; speedup vs baseline: 1.0364x; 1.0060x over previous
//
#include <hip/hip_runtime.h>
#include <hip/hip_bf16.h>
#include <stdint.h>

typedef __hip_bfloat16 bf16;
typedef __attribute__((ext_vector_type(8))) short short8;
typedef __attribute__((ext_vector_type(4))) short short4v;
typedef __attribute__((ext_vector_type(4))) float float4v;

static constexpr int nB = 2, nS = 2048, nD = 1024, nH = 16, nHD = 64;
static constexpr int nBS = nB * nS;   // 4096

#define AS_GLOBAL __attribute__((address_space(1)))
#define AS_LDS    __attribute__((address_space(3)))

union Frag16B { short8 v; uint4 u4; uint2 u2[2]; };

__device__ __forceinline__ void gload_lds16(const void* g, void* l) {
  __builtin_amdgcn_global_load_lds((AS_GLOBAL uint32_t*)(g), (AS_LDS uint32_t*)(l), 16, 0, 0);
}

__device__ __forceinline__ float fast_exp2(float x) {
#if __has_builtin(__builtin_amdgcn_exp2f)
  return __builtin_amdgcn_exp2f(x);
#else
  float r; asm volatile("v_exp_f32 %0, %1" : "=v"(r) : "v"(x)); return r;
#endif
}

// drain LDS ops but NOT vmem: prefetch global loads stay in flight across the barrier
__device__ __forceinline__ void lds_barrier() {
  asm volatile("s_waitcnt lgkmcnt(0)\ns_barrier" ::: "memory");
}

__device__ __forceinline__ void lgkm_wait() {
  asm volatile("s_waitcnt lgkmcnt(0)" ::: "memory");
}

static constexpr float SC = 0.18033688011112042f;  // 0.125 * log2(e), folded into Q at projection

// ---------------------------------------------------------------- prep: cast QKV->bf16, W->W^T bf16, rope tables
__global__ __launch_bounds__(256) void prep_kernel(
    const float* __restrict__ Qin, const float* __restrict__ Kin, const float* __restrict__ Vin,
    const float* __restrict__ Wq, const float* __restrict__ Wk,
    const float* __restrict__ Wv, const float* __restrict__ Wo,
    bf16* __restrict__ Qbf, bf16* __restrict__ Kbf, bf16* __restrict__ Vbf,
    bf16* __restrict__ WqT, bf16* __restrict__ WkT, bf16* __restrict__ WvT, bf16* __restrict__ WoT,
    bf16* __restrict__ cos_t, bf16* __restrict__ sin_t) {
  __shared__ float tile[64][65];
  int bx = blockIdx.x, t = threadIdx.x;
  if (bx < 3072) {
    int tz = bx >> 10, blk = bx & 1023;
    const float* src = tz == 0 ? Qin : tz == 1 ? Kin : Vin;
    bf16* dst = tz == 0 ? Qbf : tz == 1 ? Kbf : Vbf;
#pragma unroll
    for (int i = 0; i < 4; ++i) {
      int idx = blk * 1024 + i * 256 + t;  // float4 index
      float4 v = ((const float4*)src)[idx];
      union { bf16 b[4]; uint2 u; } tmp;
      tmp.b[0] = __float2bfloat16(v.x);
      tmp.b[1] = __float2bfloat16(v.y);
      tmp.b[2] = __float2bfloat16(v.z);
      tmp.b[3] = __float2bfloat16(v.w);
      ((uint2*)dst)[idx] = tmp.u;
    }
  } else if (bx < 4096) {
    int idx = bx - 3072;
    int z = idx >> 8;
    const float* W = z == 0 ? Wq : z == 1 ? Wk : z == 2 ? Wv : Wo;
    bf16* T = z == 0 ? WqT : z == 1 ? WkT : z == 2 ? WvT : WoT;
    int tk = (idx & 15) * 64, tn = ((idx >> 4) & 15) * 64;
    int c = t & 63, r0 = t >> 6;
#pragma unroll
    for (int i = 0; i < 16; ++i) {
      int r = i * 4 + r0;
      tile[r][c] = W[(size_t)(tk + r) * nD + tn + c];
    }
    __syncthreads();
#pragma unroll
    for (int i = 0; i < 16; ++i) {
      int r = i * 4 + r0;
      T[(size_t)(tn + r) * nD + tk + c] = __float2bfloat16(tile[c][r]);
    }
  } else {
    int base = (bx - 4096) * 1024 + t * 4;
#pragma unroll
    for (int i = 0; i < 4; ++i) {
      int e = base + i;
      int s = e >> 5, j = e & 31;
      float inv_freq = powf(100000.0f, -(float)(2 * j) / 64.0f);
      float g = (float)s * inv_freq;
      cos_t[e] = __float2bfloat16(cosf(g));
      sin_t[e] = __float2bfloat16(sinf(g));
    }
  }
}

// ---------------------------------------------------------------- fused projection GEMM v5: m97-faithful.
// 128x128 tile, BK=64, 4 waves (2Mx2N, each 64x64), SINGLE-buffered 32 KiB LDS, 2 barriers/K-step.
// Latency hiding via cross-block TLP (3 blocks/CU). Grid 768 flattened, bijective XCD swizzle.
// z==0 epilogue folds SC (attention scale * log2e) into Q, exact in f32.
__global__ __launch_bounds__(256, 3) void gemm_qkv_kernel(
    const bf16* __restrict__ A0, const bf16* __restrict__ A1, const bf16* __restrict__ A2,
    const bf16* __restrict__ Bt0, const bf16* __restrict__ Bt1, const bf16* __restrict__ Bt2,
    bf16* __restrict__ q_h, bf16* __restrict__ k_h, bf16* __restrict__ vt_h,
    const bf16* __restrict__ cos_t, const bf16* __restrict__ sin_t) {
  const int bid = blockIdx.x;
  const int swz = (bid & 7) * 96 + (bid >> 3);
  const int z = swz >> 8;            // 0..2
  const int rem = swz & 255;
  const int n0 = (rem >> 5) * 128;   // 8 n-tiles
  const int m0 = (rem & 31) * 128;   // 32 m-tiles

  const bf16* __restrict__ A  = z == 0 ? A0 : (z == 1 ? A1 : A2);
  const bf16* __restrict__ Bt = z == 0 ? Bt0 : (z == 1 ? Bt1 : Bt2);

  __shared__ bf16 As[128 * 64];   // 16 KiB
  __shared__ bf16 Bs[128 * 64];   // 16 KiB

  const int t = threadIdx.x;          // 0..255
  const int lane = t & 63;
  const int wid = t >> 6;             // 0..3
  const int quad = lane >> 4;
  const int l16 = lane & 15;
  const int r7 = l16 & 7;
  const int wm = wid >> 1;            // 0..1 -> 64 rows each
  const int wn = wid & 1;             // 0..1 -> 64 cols each (one head per wave)

  const int srow = t >> 3;                       // 0..31
  const int scg8 = ((t & 7) ^ (srow & 7)) * 8;   // swizzled k-offset (elements)

  const int ch0 = (quad ^ r7) * 8;
  const int ch1 = ch0 ^ 32;
  const int arow = (wm * 64 + l16) * 64;   // + mi*1024
  const int brow = (wn * 64 + l16) * 64;   // + ni*1024

  float4v acc[4][4] = {};

  for (int T = 0; T < 16; ++T) {
    {
      const bf16* ag_ = A + (size_t)(m0 + srow) * nD + T * 64 + scg8;
      const bf16* bg_ = Bt + (size_t)(n0 + srow) * nD + T * 64 + scg8;
#pragma unroll
      for (int i = 0; i < 4; ++i) {
        gload_lds16(ag_ + (size_t)(i * 32) * nD, As + i * 2048 + wid * 512);
        gload_lds16(bg_ + (size_t)(i * 32) * nD, Bs + i * 2048 + wid * 512);
      }
    }
    asm volatile("s_waitcnt vmcnt(0)" ::: "memory");
    __builtin_amdgcn_s_barrier();

    Frag16B fa0[4], fa1[4], fb0[4], fb1[4];
#pragma unroll
    for (int mi = 0; mi < 4; ++mi) {
      fa0[mi].u4 = *(const uint4*)&As[arow + mi * 1024 + ch0];
      fa1[mi].u4 = *(const uint4*)&As[arow + mi * 1024 + ch1];
    }
#pragma unroll
    for (int ni = 0; ni < 4; ++ni) {
      fb0[ni].u4 = *(const uint4*)&Bs[brow + ni * 1024 + ch0];
      fb1[ni].u4 = *(const uint4*)&Bs[brow + ni * 1024 + ch1];
    }

    __builtin_amdgcn_s_setprio(1);
#pragma unroll
    for (int mi = 0; mi < 4; ++mi)
#pragma unroll
      for (int ni = 0; ni < 4; ++ni)
        acc[mi][ni] = __builtin_amdgcn_mfma_f32_16x16x32_bf16(fa0[mi].v, fb0[ni].v, acc[mi][ni], 0, 0, 0);
#pragma unroll
    for (int mi = 0; mi < 4; ++mi)
#pragma unroll
      for (int ni = 0; ni < 4; ++ni)
        acc[mi][ni] = __builtin_amdgcn_mfma_f32_16x16x32_bf16(fa1[mi].v, fb1[ni].v, acc[mi][ni], 0, 0, 0);
    __builtin_amdgcn_s_setprio(0);

    __builtin_amdgcn_s_barrier();
  }

  // ---- epilogue: RoPE + RMSNorm (q,k) or transposed store (v)
  const int col0 = n0 + wn * 64;   // multiple of 64 -> one head per wave
  if (z <= 1) {
    bf16* dst = z ? k_h : q_h;
#pragma unroll
    for (int mi = 0; mi < 4; ++mi)
#pragma unroll
      for (int r = 0; r < 4; ++r) {
        int row = m0 + wm * 64 + mi * 16 + quad * 4 + r;
        int s = row & (nS - 1);
        float x0 = acc[mi][0][r], x1 = acc[mi][1][r], x2 = acc[mi][2][r], x3 = acc[mi][3][r];
        float y[4];
#pragma unroll
        for (int p = 0; p < 2; ++p) {
          int d = p * 16 + l16;
          float c = __bfloat162float(cos_t[s * 32 + d]);
          float sn = __bfloat162float(sin_t[s * 32 + d]);
          float xa = p ? x1 : x0, xb = p ? x3 : x2;
          y[p] = xa * c + xb * sn;
          y[p + 2] = xb * c - xa * sn;
        }
        float ss = y[0] * y[0] + y[1] * y[1] + y[2] * y[2] + y[3] * y[3];
#pragma unroll
        for (int m = 1; m <= 8; m <<= 1) ss += __shfl_xor(ss, m, 64);
        float inv = 1.0f / sqrtf(ss * (1.0f / 64.0f) + 1e-9f);
        if (z == 0) inv *= SC;   // fold attention scale*log2e into Q (f32-exact)
#pragma unroll
        for (int ni = 0; ni < 4; ++ni)
          dst[(size_t)row * nD + col0 + ni * 16 + l16] = __float2bfloat16(y[ni] * inv);
      }
  } else {
    // V: write transposed -> vt_h [b][h][d][s]
#pragma unroll
    for (int mi = 0; mi < 4; ++mi)
#pragma unroll
      for (int r = 0; r < 4; ++r) {
        int row = m0 + wm * 64 + mi * 16 + quad * 4 + r;
        int b = row >> 11, s = row & (nS - 1);
#pragma unroll
        for (int ni = 0; ni < 4; ++ni) {
          int col = col0 + ni * 16 + l16;
          int h = col >> 6, d = col & 63;
          vt_h[((size_t)((b * nH + h) * 64 + d)) * nS + s] = __float2bfloat16(acc[mi][ni][r]);
        }
      }
  }
}

// ---------------------------------------------------------------- output GEMM v2: 64x128 tile, BK=64,
// double-buffered 48 KiB LDS, ONE barrier per K-step. Grid 512 flattened, n-major.
__global__ __launch_bounds__(256, 2) void gemm_out_kernel(
    const bf16* __restrict__ A, const bf16* __restrict__ Bt, float* __restrict__ C) {
  __shared__ bf16 As[2 * 64 * 64];    // 16 KiB
  __shared__ bf16 Bs[2 * 128 * 64];   // 32 KiB
  const int bid = blockIdx.x;         // 0..511
  const int n0 = (bid & 7) * 128;
  const int m0 = (bid >> 3) * 64;
  const int t = threadIdx.x;
  const int lane = t & 63;
  const int wid = t >> 6;
  const int quad = lane >> 4;
  const int l16 = lane & 15;
  const int r7 = l16 & 7;
  const int wm = wid >> 1;
  const int wn = wid & 1;

  const int srow = t >> 3;                       // 0..31
  const int scg8 = ((t & 7) ^ (srow & 7)) * 8;

  const int ch0 = (quad ^ r7) * 8;
  const int ch1 = ch0 ^ 32;
  const int arow = (wm * 32 + l16) * 64;   // + mi*1024 (+buf)
  const int brow = (wn * 64 + l16) * 64;   // + ni*1024 (+buf)

#define STAGE_O(KT, AB, BB) do { \
    const bf16* ag_ = A + (size_t)(m0 + srow) * nD + (KT) * 64 + scg8; \
    const bf16* bg_ = Bt + (size_t)(n0 + srow) * nD + (KT) * 64 + scg8; \
    gload_lds16(ag_, As + (AB) + wid * 512); \
    gload_lds16(ag_ + (size_t)32 * nD, As + (AB) + 2048 + wid * 512); \
    _Pragma("unroll") \
    for (int i = 0; i < 4; ++i) \
      gload_lds16(bg_ + (size_t)(i * 32) * nD, Bs + (BB) + i * 2048 + wid * 512); \
  } while (0)

  float4v acc[2][4] = {};

  STAGE_O(0, 0, 0);
  asm volatile("s_waitcnt vmcnt(0)" ::: "memory");
  __builtin_amdgcn_s_barrier();

#pragma unroll 2
  for (int T = 0; T < 16; ++T) {
    const int cua = (T & 1) * 4096;
    const int cub = (T & 1) * 8192;

    if (T < 15) STAGE_O(T + 1, cua ^ 4096, cub ^ 8192);

    Frag16B a0[2], a1[2], b0[4], b1[4];
#pragma unroll
    for (int mi = 0; mi < 2; ++mi) {
      a0[mi].u4 = *(const uint4*)&As[cua + arow + mi * 1024 + ch0];
      a1[mi].u4 = *(const uint4*)&As[cua + arow + mi * 1024 + ch1];
    }
#pragma unroll
    for (int ni = 0; ni < 4; ++ni) {
      b0[ni].u4 = *(const uint4*)&Bs[cub + brow + ni * 1024 + ch0];
      b1[ni].u4 = *(const uint4*)&Bs[cub + brow + ni * 1024 + ch1];
    }

    __builtin_amdgcn_s_setprio(1);
#pragma unroll
    for (int mi = 0; mi < 2; ++mi)
#pragma unroll
      for (int ni = 0; ni < 4; ++ni)
        acc[mi][ni] = __builtin_amdgcn_mfma_f32_16x16x32_bf16(a0[mi].v, b0[ni].v, acc[mi][ni], 0, 0, 0);
#pragma unroll
    for (int mi = 0; mi < 2; ++mi)
#pragma unroll
      for (int ni = 0; ni < 4; ++ni)
        acc[mi][ni] = __builtin_amdgcn_mfma_f32_16x16x32_bf16(a1[mi].v, b1[ni].v, acc[mi][ni], 0, 0, 0);
    __builtin_amdgcn_s_setprio(0);

    asm volatile("s_waitcnt vmcnt(0)" ::: "memory");
    __builtin_amdgcn_s_barrier();
  }
#undef STAGE_O

#pragma unroll
  for (int mi = 0; mi < 2; ++mi)
#pragma unroll
    for (int ni = 0; ni < 4; ++ni)
#pragma unroll
      for (int r = 0; r < 4; ++r) {
        int row = m0 + wm * 32 + mi * 16 + quad * 4 + r;
        int col = n0 + wn * 64 + ni * 16 + l16;
        C[(size_t)row * nD + col] = acc[mi][ni][r];
      }
}

// ---------------------------------------------------------------- flash attention v8b: KVBLK=128, 8-wave blocks,
// wave owns 16 q-rows. Main loop = full unmasked 128-key tiles (branchless); final diagonal tile
// handles all masking. K/V via global_load_lds, double-buffered 64 KiB LDS (2 blocks/CU),
// one vmcnt(0)+lgkm(0)+barrier per 128 keys. Q arrives pre-scaled by SC (folded in gemm_qkv).
__global__ __launch_bounds__(512, 4) void attn_kernel(const bf16* __restrict__ q_h,
                                                      const bf16* __restrict__ k_h,
                                                      const bf16* __restrict__ vt_h,
                                                      bf16* __restrict__ vals) {
  __shared__ bf16 lds_buf[4 * 8192];   // [K0|K1|V0|V1], 8192 elems each: K=128x64, V=2 half-subtiles 64x64

  const int t = threadIdx.x;           // 0..511
  const int lane = t & 63, wid = t >> 6, quad = lane >> 4, l16 = lane & 15;
  const int id = blockIdx.x;           // 0..511
  const int xcd = id & 7;              // round-robin XCD heuristic
  const int j = id >> 3;               // 0..63 per-XCD index
  const int jj = j & 31;
  const int bh = xcd * 4 + (jj & 3);   // 4 heads per XCD; pair blocks share bh
  const int u = jj >> 2;               // 0..7
  const int qt = (j < 32) ? (15 - u) : u;   // first CU-slot: long tiles; second: complementary short
  const int b = bh >> 4, h = bh & 15;

  const bf16* Kbase = k_h + ((size_t)b * nS) * nD + h * 64;
  const bf16* Vbase = vt_h + (size_t)bh * 64 * nS;  // [d][s]

  const int rl = lane >> 3;               // 0..7
  const int cg8 = ((lane & 7) ^ rl) * 8;  // pre-swizzled source chunk (elem offset)
  const int r7 = l16 & 7;

  bf16* const scratch = lds_buf + wid * 1152;  // 16 x 72 per wave (epilogue only)

  const int q0w = qt * 128 + wid * 16;         // wave's first q row

  // Q B-frags (col=q=l16, k=d), 2 d-halves
  Frag16B qf[2];
  {
    const bf16* qp = q_h + ((size_t)(b * nS + q0w + l16)) * nD + h * 64;
    qf[0].u4 = *(const uint4*)(qp + quad * 8);
    qf[1].u4 = *(const uint4*)(qp + 32 + quad * 8);
  }

  // stage 128-key K/V tile KT into buffer (KT&1): linear LDS dest, swizzled global source
#define STAGE_KV(KT) do { \
    const int bo_ = ((KT) & 1) * 8192; \
    const bf16* kg_ = Kbase + (size_t)((KT) * 128 + wid * 16 + rl) * nD + cg8; \
    gload_lds16(kg_, lds_buf + bo_ + wid * 1024); \
    gload_lds16(kg_ + (size_t)8 * nD, lds_buf + bo_ + wid * 1024 + 512); \
    const bf16* vg_ = Vbase + (size_t)(wid * 8 + rl) * nS + (KT) * 128 + cg8; \
    gload_lds16(vg_, lds_buf + 16384 + bo_ + wid * 512); \
    gload_lds16(vg_ + 64, lds_buf + 16384 + bo_ + 4096 + wid * 512); \
  } while (0)

  // QK^T for half HB of current K tile -> ST (S^T frags, key=row)
#define QKH(Kb, HB, ST) do { \
    _Pragma("unroll") \
    for (int kt4 = 0; kt4 < 4; ++kt4) { \
      int row = (HB) * 64 + kt4 * 16 + l16; \
      Frag16B k0_, k1_; \
      k0_.u4 = *(const uint4*)&(Kb)[row * 64 + ((quad ^ r7) * 8)]; \
      k1_.u4 = *(const uint4*)&(Kb)[row * 64 + (((quad + 4) ^ r7) * 8)]; \
      float4v zz_ = {}; \
      zz_ = __builtin_amdgcn_mfma_f32_16x16x32_bf16(k0_.v, qf[0].v, zz_, 0, 0, 0); \
      (ST)[kt4] = __builtin_amdgcn_mfma_f32_16x16x32_bf16(k1_.v, qf[1].v, zz_, 0, 0, 0); \
    } \
  } while (0)

  // exp (unmasked) ST -> PF, accumulate l_acc (Q pre-scaled: no per-element SC mul)
#define EXPH(ST, PF) do { \
    _Pragma("unroll") \
    for (int kt4 = 0; kt4 < 4; ++kt4) \
      _Pragma("unroll") \
      for (int r = 0; r < 4; ++r) { \
        float p_ = fast_exp2((ST)[kt4][r]); \
        l_acc += p_; \
        union { bf16 hh; short ss; } cv_; \
        cv_.hh = __float2bfloat16(p_); \
        (PF)[kt4][r] = cv_.ss; \
      } \
  } while (0)

  // exp (masked, diagonal tile) for half HB
#define EXPHM(ST, PF, HB) do { \
    int qg_ = q0w + l16; \
    _Pragma("unroll") \
    for (int kt4 = 0; kt4 < 4; ++kt4) { \
      int key0_ = qt * 128 + (HB) * 64 + kt4 * 16 + quad * 4; \
      _Pragma("unroll") \
      for (int r = 0; r < 4; ++r) { \
        float x_ = (ST)[kt4][r]; \
        if (key0_ + r > qg_) x_ = -12000.0f; \
        float p_ = fast_exp2(x_); \
        l_acc += p_; \
        union { bf16 hh; short ss; } cv_; \
        cv_.hh = __float2bfloat16(p_); \
        (PF)[kt4][r] = cv_.ss; \
      } \
    } \
  } while (0)

  // O^T += V^T(half HB) . P^T
#define PVH(Vb, HB, PF) do { \
    _Pragma("unroll") \
    for (int dt = 0; dt < 4; ++dt) { \
      int row = dt * 16 + l16; \
      _Pragma("unroll") \
      for (int kt4 = 0; kt4 < 4; ++kt4) { \
        int chunk_ = kt4 * 2 + (quad >> 1); \
        union { uint2 u; short4v s; } vv_; \
        vv_.u = *(const uint2*)&(Vb)[(HB) * 4096 + row * 64 + ((chunk_ ^ r7) * 8) + (quad & 1) * 4]; \
        o_acc[dt] = __builtin_amdgcn_mfma_f32_16x16x16bf16_1k(vv_.s, (PF)[kt4], o_acc[dt], 0, 0, 0); \
      } \
    } \
  } while (0)

  STAGE_KV(0);
  asm volatile("s_waitcnt vmcnt(0)" ::: "memory");
  __builtin_amdgcn_s_barrier();

  float4v o_acc[4] = {};
  float l_acc = 0.f;

  // ---- main loop: full unmasked tiles (branchless)
  for (int kt = 0; kt < qt; ++kt) {
    STAGE_KV(kt + 1);
    const bf16* Kb = lds_buf + (kt & 1) * 8192;
    const bf16* Vb = lds_buf + 16384 + (kt & 1) * 8192;

    float4v st0[4], st1[4];
    __builtin_amdgcn_s_setprio(1);
    QKH(Kb, 0, st0);
    QKH(Kb, 1, st1);
    __builtin_amdgcn_s_setprio(0);

    short4v pf[4];
    EXPH(st0, pf);
    __builtin_amdgcn_s_setprio(1);
    PVH(Vb, 0, pf);
    __builtin_amdgcn_s_setprio(0);
    EXPH(st1, pf);
    __builtin_amdgcn_s_setprio(1);
    PVH(Vb, 1, pf);
    __builtin_amdgcn_s_setprio(0);

    asm volatile("s_waitcnt vmcnt(0) lgkmcnt(0)" ::: "memory");
    __builtin_amdgcn_s_barrier();
  }

  // ---- final diagonal tile kt = qt (no prefetch; all masking lives here)
  {
    const bf16* Kb = lds_buf + (qt & 1) * 8192;
    const bf16* Vb = lds_buf + 16384 + (qt & 1) * 8192;

    float4v st0[4];
    QKH(Kb, 0, st0);
    short4v pf[4];
    EXPHM(st0, pf, 0);
    PVH(Vb, 0, pf);

    if (wid >= 4) {   // waves 0-3: h1 keys are all > q0w+15 (fully masked) -> skip
      float4v st1[4];
      QKH(Kb, 1, st1);
      EXPHM(st1, pf, 1);
      PVH(Vb, 1, pf);
    }
  }
#undef STAGE_KV
#undef QKH
#undef EXPH
#undef EXPHM
#undef PVH

  // all waves done reading K/V before scratch (overlapping K region) is overwritten
  lds_barrier();

  // ---- epilogue: row-sum reduce, LDS-transpose, coalesced 16B stores
  float la = l_acc;
  la += __shfl_xor(la, 16, 64);
  la += __shfl_xor(la, 32, 64);
  float inv_l = 1.0f / la;
  // write transposed: scratch[q_loc=l16][d]
#pragma unroll
  for (int dt = 0; dt < 4; ++dt) {
    union { bf16 b2[2]; uint u; } p01, p23;
    p01.b2[0] = __float2bfloat16(o_acc[dt][0] * inv_l);
    p01.b2[1] = __float2bfloat16(o_acc[dt][1] * inv_l);
    p23.b2[0] = __float2bfloat16(o_acc[dt][2] * inv_l);
    p23.b2[1] = __float2bfloat16(o_acc[dt][3] * inv_l);
    *(uint*)&scratch[l16 * 72 + dt * 16 + quad * 4] = p01.u;
    *(uint*)&scratch[l16 * 72 + dt * 16 + quad * 4 + 2] = p23.u;
  }
  lgkm_wait();  // own writes visible to own reads
  uint4 r0 = *(const uint4*)&scratch[l16 * 72 + quad * 16];
  uint4 r1 = *(const uint4*)&scratch[l16 * 72 + quad * 16 + 8];
  int qrow = q0w + l16;
  bf16* vp = vals + ((size_t)(b * nS + qrow)) * nD + h * 64 + quad * 16;
  *(uint4*)(vp) = r0;
  *(uint4*)(vp + 8) = r1;
}

// ---------------------------------------------------------------- launch
extern "C" void kernel_launch(void* const* d_in, const int* in_sizes, int n_in,
                              void* d_out, int out_size, void* d_ws, size_t ws_size,
                              hipStream_t stream) {
  const float* Qin = (const float*)d_in[0];
  const float* Kin = (const float*)d_in[1];
  const float* Vin = (const float*)d_in[2];
  const float* Wq = (const float*)d_in[4];
  const float* Wk = (const float*)d_in[5];
  const float* Wv = (const float*)d_in[6];
  const float* Wo = (const float*)d_in[7];
  float* out = (float*)d_out;

  char* ws = (char*)d_ws;
  const size_t MB = 1u << 20;
  bf16* Qbf = (bf16*)(ws + 0 * MB);
  bf16* Kbf = (bf16*)(ws + 8 * MB);
  bf16* Vbf = (bf16*)(ws + 16 * MB);
  bf16* WqT = (bf16*)(ws + 24 * MB);
  bf16* WkT = (bf16*)(ws + 26 * MB);
  bf16* WvT = (bf16*)(ws + 28 * MB);
  bf16* WoT = (bf16*)(ws + 30 * MB);
  bf16* cos_t = (bf16*)(ws + 32 * MB);
  bf16* sin_t = (bf16*)(ws + 33 * MB);
  bf16* q_h = (bf16*)(ws + 34 * MB);
  bf16* k_h = (bf16*)(ws + 42 * MB);
  bf16* vt_h = (bf16*)(ws + 50 * MB);
  bf16* vals = (bf16*)(ws + 58 * MB);

  prep_kernel<<<4160, 256, 0, stream>>>(Qin, Kin, Vin, Wq, Wk, Wv, Wo,
                                        Qbf, Kbf, Vbf, WqT, WkT, WvT, WoT, cos_t, sin_t);

  gemm_qkv_kernel<<<768, 256, 0, stream>>>(Qbf, Kbf, Vbf, WqT, WkT, WvT,
                                           q_h, k_h, vt_h, cos_t, sin_t);

  attn_kernel<<<512, 512, 0, stream>>>(q_h, k_h, vt_h, vals);

  gemm_out_kernel<<<512, 256, 0, stream>>>(vals, WoT, out);
}

// Round 13
// 202.241 us; speedup vs baseline: 1.0709x; 1.0333x over previous
//
#include <hip/hip_runtime.h>
#include <hip/hip_bf16.h>
#include <stdint.h>

typedef __hip_bfloat16 bf16;
typedef __attribute__((ext_vector_type(8))) short short8;
typedef __attribute__((ext_vector_type(4))) short short4v;
typedef __attribute__((ext_vector_type(4))) float float4v;

static constexpr int nB = 2, nS = 2048, nD = 1024, nH = 16, nHD = 64;
static constexpr int nBS = nB * nS;   // 4096

#define AS_GLOBAL __attribute__((address_space(1)))
#define AS_LDS    __attribute__((address_space(3)))

union Frag16B { short8 v; uint4 u4; uint2 u2[2]; };

__device__ __forceinline__ void gload_lds16(const void* g, void* l) {
  __builtin_amdgcn_global_load_lds((AS_GLOBAL uint32_t*)(g), (AS_LDS uint32_t*)(l), 16, 0, 0);
}

__device__ __forceinline__ float fast_exp2(float x) {
#if __has_builtin(__builtin_amdgcn_exp2f)
  return __builtin_amdgcn_exp2f(x);
#else
  float r; asm volatile("v_exp_f32 %0, %1" : "=v"(r) : "v"(x)); return r;
#endif
}

// drain LDS ops but NOT vmem: prefetch global loads stay in flight across the barrier
__device__ __forceinline__ void lds_barrier() {
  asm volatile("s_waitcnt lgkmcnt(0)\ns_barrier" ::: "memory");
}

__device__ __forceinline__ void lgkm_wait() {
  asm volatile("s_waitcnt lgkmcnt(0)" ::: "memory");
}

static constexpr float SC = 0.18033688011112042f;  // 0.125 * log2(e), folded into Q at projection

// ---------------------------------------------------------------- prep: cast QKV->bf16, W->W^T bf16, rope tables
__global__ __launch_bounds__(256) void prep_kernel(
    const float* __restrict__ Qin, const float* __restrict__ Kin, const float* __restrict__ Vin,
    const float* __restrict__ Wq, const float* __restrict__ Wk,
    const float* __restrict__ Wv, const float* __restrict__ Wo,
    bf16* __restrict__ Qbf, bf16* __restrict__ Kbf, bf16* __restrict__ Vbf,
    bf16* __restrict__ WqT, bf16* __restrict__ WkT, bf16* __restrict__ WvT, bf16* __restrict__ WoT,
    bf16* __restrict__ cos_t, bf16* __restrict__ sin_t) {
  __shared__ float tile[64][65];
  int bx = blockIdx.x, t = threadIdx.x;
  if (bx < 3072) {
    int tz = bx >> 10, blk = bx & 1023;
    const float* src = tz == 0 ? Qin : tz == 1 ? Kin : Vin;
    bf16* dst = tz == 0 ? Qbf : tz == 1 ? Kbf : Vbf;
#pragma unroll
    for (int i = 0; i < 4; ++i) {
      int idx = blk * 1024 + i * 256 + t;  // float4 index
      float4 v = ((const float4*)src)[idx];
      union { bf16 b[4]; uint2 u; } tmp;
      tmp.b[0] = __float2bfloat16(v.x);
      tmp.b[1] = __float2bfloat16(v.y);
      tmp.b[2] = __float2bfloat16(v.z);
      tmp.b[3] = __float2bfloat16(v.w);
      ((uint2*)dst)[idx] = tmp.u;
    }
  } else if (bx < 4096) {
    int idx = bx - 3072;
    int z = idx >> 8;
    const float* W = z == 0 ? Wq : z == 1 ? Wk : z == 2 ? Wv : Wo;
    bf16* T = z == 0 ? WqT : z == 1 ? WkT : z == 2 ? WvT : WoT;
    int tk = (idx & 15) * 64, tn = ((idx >> 4) & 15) * 64;
    int c = t & 63, r0 = t >> 6;
#pragma unroll
    for (int i = 0; i < 16; ++i) {
      int r = i * 4 + r0;
      tile[r][c] = W[(size_t)(tk + r) * nD + tn + c];
    }
    __syncthreads();
#pragma unroll
    for (int i = 0; i < 16; ++i) {
      int r = i * 4 + r0;
      T[(size_t)(tn + r) * nD + tk + c] = __float2bfloat16(tile[c][r]);
    }
  } else {
    int base = (bx - 4096) * 1024 + t * 4;
#pragma unroll
    for (int i = 0; i < 4; ++i) {
      int e = base + i;
      int s = e >> 5, j = e & 31;
      float inv_freq = powf(100000.0f, -(float)(2 * j) / 64.0f);
      float g = (float)s * inv_freq;
      cos_t[e] = __float2bfloat16(cosf(g));
      sin_t[e] = __float2bfloat16(sinf(g));
    }
  }
}

// ---------------------------------------------------------------- fused projection GEMM v6: m97-faithful + 4 blocks/CU.
// 128x128 tile, BK=64, 4 waves (2Mx2N, each 64x64), SINGLE-buffered 32 KiB LDS, 2 barriers/K-step.
// K-step split into two frag-load/MFMA halves (kk0 then kk1) to halve frag liveness -> VGPR<=128
// -> __launch_bounds__(256,4) = 4 blocks/CU (16 waves) of cross-block TLP hiding the vmcnt drain.
// Per-element accumulation order unchanged. Grid 768 flattened, bijective XCD swizzle.
// z==0 epilogue folds SC (attention scale * log2e) into Q, exact in f32.
__global__ __launch_bounds__(256, 4) void gemm_qkv_kernel(
    const bf16* __restrict__ A0, const bf16* __restrict__ A1, const bf16* __restrict__ A2,
    const bf16* __restrict__ Bt0, const bf16* __restrict__ Bt1, const bf16* __restrict__ Bt2,
    bf16* __restrict__ q_h, bf16* __restrict__ k_h, bf16* __restrict__ vt_h,
    const bf16* __restrict__ cos_t, const bf16* __restrict__ sin_t) {
  const int bid = blockIdx.x;
  const int swz = (bid & 7) * 96 + (bid >> 3);
  const int z = swz >> 8;            // 0..2
  const int rem = swz & 255;
  const int n0 = (rem >> 5) * 128;   // 8 n-tiles
  const int m0 = (rem & 31) * 128;   // 32 m-tiles

  const bf16* __restrict__ A  = z == 0 ? A0 : (z == 1 ? A1 : A2);
  const bf16* __restrict__ Bt = z == 0 ? Bt0 : (z == 1 ? Bt1 : Bt2);

  __shared__ bf16 As[128 * 64];   // 16 KiB
  __shared__ bf16 Bs[128 * 64];   // 16 KiB

  const int t = threadIdx.x;          // 0..255
  const int lane = t & 63;
  const int wid = t >> 6;             // 0..3
  const int quad = lane >> 4;
  const int l16 = lane & 15;
  const int r7 = l16 & 7;
  const int wm = wid >> 1;            // 0..1 -> 64 rows each
  const int wn = wid & 1;             // 0..1 -> 64 cols each (one head per wave)

  const int srow = t >> 3;                       // 0..31
  const int scg8 = ((t & 7) ^ (srow & 7)) * 8;   // swizzled k-offset (elements)

  const int ch0 = (quad ^ r7) * 8;
  const int ch1 = ch0 ^ 32;
  const int arow = (wm * 64 + l16) * 64;   // + mi*1024
  const int brow = (wn * 64 + l16) * 64;   // + ni*1024

  float4v acc[4][4] = {};

  for (int T = 0; T < 16; ++T) {
    // ---- stage tile T into the (single) buffer
    {
      const bf16* ag_ = A + (size_t)(m0 + srow) * nD + T * 64 + scg8;
      const bf16* bg_ = Bt + (size_t)(n0 + srow) * nD + T * 64 + scg8;
#pragma unroll
      for (int i = 0; i < 4; ++i) {
        gload_lds16(ag_ + (size_t)(i * 32) * nD, As + i * 2048 + wid * 512);
        gload_lds16(bg_ + (size_t)(i * 32) * nD, Bs + i * 2048 + wid * 512);
      }
    }
    asm volatile("s_waitcnt vmcnt(0)" ::: "memory");
    __builtin_amdgcn_s_barrier();

    // ---- kk0 half: load 8 frags, 16 MFMA
    Frag16B fa[4], fb[4];
#pragma unroll
    for (int mi = 0; mi < 4; ++mi) fa[mi].u4 = *(const uint4*)&As[arow + mi * 1024 + ch0];
#pragma unroll
    for (int ni = 0; ni < 4; ++ni) fb[ni].u4 = *(const uint4*)&Bs[brow + ni * 1024 + ch0];
    __builtin_amdgcn_s_setprio(1);
#pragma unroll
    for (int mi = 0; mi < 4; ++mi)
#pragma unroll
      for (int ni = 0; ni < 4; ++ni)
        acc[mi][ni] = __builtin_amdgcn_mfma_f32_16x16x32_bf16(fa[mi].v, fb[ni].v, acc[mi][ni], 0, 0, 0);
    __builtin_amdgcn_s_setprio(0);

    // ---- kk1 half: reuse frag regs, 16 MFMA
#pragma unroll
    for (int mi = 0; mi < 4; ++mi) fa[mi].u4 = *(const uint4*)&As[arow + mi * 1024 + ch1];
#pragma unroll
    for (int ni = 0; ni < 4; ++ni) fb[ni].u4 = *(const uint4*)&Bs[brow + ni * 1024 + ch1];
    __builtin_amdgcn_s_setprio(1);
#pragma unroll
    for (int mi = 0; mi < 4; ++mi)
#pragma unroll
      for (int ni = 0; ni < 4; ++ni)
        acc[mi][ni] = __builtin_amdgcn_mfma_f32_16x16x32_bf16(fa[mi].v, fb[ni].v, acc[mi][ni], 0, 0, 0);
    __builtin_amdgcn_s_setprio(0);

    __builtin_amdgcn_s_barrier();   // all waves done reading before next T's stage overwrites
  }

  // ---- epilogue: RoPE + RMSNorm (q,k) or transposed store (v)
  const int col0 = n0 + wn * 64;   // multiple of 64 -> one head per wave
  if (z <= 1) {
    bf16* dst = z ? k_h : q_h;
#pragma unroll
    for (int mi = 0; mi < 4; ++mi)
#pragma unroll
      for (int r = 0; r < 4; ++r) {
        int row = m0 + wm * 64 + mi * 16 + quad * 4 + r;
        int s = row & (nS - 1);
        float x0 = acc[mi][0][r], x1 = acc[mi][1][r], x2 = acc[mi][2][r], x3 = acc[mi][3][r];
        float y[4];
#pragma unroll
        for (int p = 0; p < 2; ++p) {
          int d = p * 16 + l16;
          float c = __bfloat162float(cos_t[s * 32 + d]);
          float sn = __bfloat162float(sin_t[s * 32 + d]);
          float xa = p ? x1 : x0, xb = p ? x3 : x2;
          y[p] = xa * c + xb * sn;
          y[p + 2] = xb * c - xa * sn;
        }
        float ss = y[0] * y[0] + y[1] * y[1] + y[2] * y[2] + y[3] * y[3];
#pragma unroll
        for (int m = 1; m <= 8; m <<= 1) ss += __shfl_xor(ss, m, 64);
        float inv = 1.0f / sqrtf(ss * (1.0f / 64.0f) + 1e-9f);
        if (z == 0) inv *= SC;   // fold attention scale*log2e into Q (f32-exact)
#pragma unroll
        for (int ni = 0; ni < 4; ++ni)
          dst[(size_t)row * nD + col0 + ni * 16 + l16] = __float2bfloat16(y[ni] * inv);
      }
  } else {
    // V: write transposed -> vt_h [b][h][d][s]
#pragma unroll
    for (int mi = 0; mi < 4; ++mi)
#pragma unroll
      for (int r = 0; r < 4; ++r) {
        int row = m0 + wm * 64 + mi * 16 + quad * 4 + r;
        int b = row >> 11, s = row & (nS - 1);
#pragma unroll
        for (int ni = 0; ni < 4; ++ni) {
          int col = col0 + ni * 16 + l16;
          int h = col >> 6, d = col & 63;
          vt_h[((size_t)((b * nH + h) * 64 + d)) * nS + s] = __float2bfloat16(acc[mi][ni][r]);
        }
      }
  }
}

// ---------------------------------------------------------------- output GEMM v3: 64x128 tile, BK=64,
// double-buffered 48 KiB LDS, ONE barrier per K-step, now 3 blocks/CU (144 KiB LDS of 160).
__global__ __launch_bounds__(256, 3) void gemm_out_kernel(
    const bf16* __restrict__ A, const bf16* __restrict__ Bt, float* __restrict__ C) {
  __shared__ bf16 As[2 * 64 * 64];    // 16 KiB
  __shared__ bf16 Bs[2 * 128 * 64];   // 32 KiB
  const int bid = blockIdx.x;         // 0..511
  const int n0 = (bid & 7) * 128;
  const int m0 = (bid >> 3) * 64;
  const int t = threadIdx.x;
  const int lane = t & 63;
  const int wid = t >> 6;
  const int quad = lane >> 4;
  const int l16 = lane & 15;
  const int r7 = l16 & 7;
  const int wm = wid >> 1;
  const int wn = wid & 1;

  const int srow = t >> 3;                       // 0..31
  const int scg8 = ((t & 7) ^ (srow & 7)) * 8;

  const int ch0 = (quad ^ r7) * 8;
  const int ch1 = ch0 ^ 32;
  const int arow = (wm * 32 + l16) * 64;   // + mi*1024 (+buf)
  const int brow = (wn * 64 + l16) * 64;   // + ni*1024 (+buf)

#define STAGE_O(KT, AB, BB) do { \
    const bf16* ag_ = A + (size_t)(m0 + srow) * nD + (KT) * 64 + scg8; \
    const bf16* bg_ = Bt + (size_t)(n0 + srow) * nD + (KT) * 64 + scg8; \
    gload_lds16(ag_, As + (AB) + wid * 512); \
    gload_lds16(ag_ + (size_t)32 * nD, As + (AB) + 2048 + wid * 512); \
    _Pragma("unroll") \
    for (int i = 0; i < 4; ++i) \
      gload_lds16(bg_ + (size_t)(i * 32) * nD, Bs + (BB) + i * 2048 + wid * 512); \
  } while (0)

  float4v acc[2][4] = {};

  STAGE_O(0, 0, 0);
  asm volatile("s_waitcnt vmcnt(0)" ::: "memory");
  __builtin_amdgcn_s_barrier();

#pragma unroll 2
  for (int T = 0; T < 16; ++T) {
    const int cua = (T & 1) * 4096;
    const int cub = (T & 1) * 8192;

    if (T < 15) STAGE_O(T + 1, cua ^ 4096, cub ^ 8192);

    Frag16B a0[2], a1[2], b0[4], b1[4];
#pragma unroll
    for (int mi = 0; mi < 2; ++mi) {
      a0[mi].u4 = *(const uint4*)&As[cua + arow + mi * 1024 + ch0];
      a1[mi].u4 = *(const uint4*)&As[cua + arow + mi * 1024 + ch1];
    }
#pragma unroll
    for (int ni = 0; ni < 4; ++ni) {
      b0[ni].u4 = *(const uint4*)&Bs[cub + brow + ni * 1024 + ch0];
      b1[ni].u4 = *(const uint4*)&Bs[cub + brow + ni * 1024 + ch1];
    }

    __builtin_amdgcn_s_setprio(1);
#pragma unroll
    for (int mi = 0; mi < 2; ++mi)
#pragma unroll
      for (int ni = 0; ni < 4; ++ni)
        acc[mi][ni] = __builtin_amdgcn_mfma_f32_16x16x32_bf16(a0[mi].v, b0[ni].v, acc[mi][ni], 0, 0, 0);
#pragma unroll
    for (int mi = 0; mi < 2; ++mi)
#pragma unroll
      for (int ni = 0; ni < 4; ++ni)
        acc[mi][ni] = __builtin_amdgcn_mfma_f32_16x16x32_bf16(a1[mi].v, b1[ni].v, acc[mi][ni], 0, 0, 0);
    __builtin_amdgcn_s_setprio(0);

    asm volatile("s_waitcnt vmcnt(0)" ::: "memory");
    __builtin_amdgcn_s_barrier();
  }
#undef STAGE_O

#pragma unroll
  for (int mi = 0; mi < 2; ++mi)
#pragma unroll
    for (int ni = 0; ni < 4; ++ni)
#pragma unroll
      for (int r = 0; r < 4; ++r) {
        int row = m0 + wm * 32 + mi * 16 + quad * 4 + r;
        int col = n0 + wn * 64 + ni * 16 + l16;
        C[(size_t)row * nD + col] = acc[mi][ni][r];
      }
}

// ---------------------------------------------------------------- flash attention v8c: KVBLK=128, 8-wave blocks,
// wave owns 16 q-rows. Main loop = full unmasked 128-key tiles (branchless); final diagonal tile
// handles all masking. K/V via global_load_lds, double-buffered 64 KiB LDS (2 blocks/CU),
// one vmcnt(0)+lgkm(0)+barrier per 128 keys. Q pre-scaled by SC.
// NEW: l computed via MFMA ones-trick (A=all-ones 16x16 -> every C row = sum_k P[k][q]) —
// removes 32 VALU adds/tile + the epilogue shfl pair; l sums the same bf16-rounded P that PV uses.
__global__ __launch_bounds__(512, 4) void attn_kernel(const bf16* __restrict__ q_h,
                                                      const bf16* __restrict__ k_h,
                                                      const bf16* __restrict__ vt_h,
                                                      bf16* __restrict__ vals) {
  __shared__ bf16 lds_buf[4 * 8192];   // [K0|K1|V0|V1], 8192 elems each: K=128x64, V=2 half-subtiles 64x64

  const int t = threadIdx.x;           // 0..511
  const int lane = t & 63, wid = t >> 6, quad = lane >> 4, l16 = lane & 15;
  const int id = blockIdx.x;           // 0..511
  const int xcd = id & 7;              // round-robin XCD heuristic
  const int j = id >> 3;               // 0..63 per-XCD index
  const int jj = j & 31;
  const int bh = xcd * 4 + (jj & 3);   // 4 heads per XCD; pair blocks share bh
  const int u = jj >> 2;               // 0..7
  const int qt = (j < 32) ? (15 - u) : u;   // first CU-slot: long tiles; second: complementary short
  const int b = bh >> 4, h = bh & 15;

  const bf16* Kbase = k_h + ((size_t)b * nS) * nD + h * 64;
  const bf16* Vbase = vt_h + (size_t)bh * 64 * nS;  // [d][s]

  const int rl = lane >> 3;               // 0..7
  const int cg8 = ((lane & 7) ^ rl) * 8;  // pre-swizzled source chunk (elem offset)
  const int r7 = l16 & 7;

  bf16* const scratch = lds_buf + wid * 1152;  // 16 x 72 per wave (epilogue only)

  const int q0w = qt * 128 + wid * 16;         // wave's first q row

  const short4v vones = {(short)0x3F80, (short)0x3F80, (short)0x3F80, (short)0x3F80};  // bf16 1.0 x4

  // Q B-frags (col=q=l16, k=d), 2 d-halves
  Frag16B qf[2];
  {
    const bf16* qp = q_h + ((size_t)(b * nS + q0w + l16)) * nD + h * 64;
    qf[0].u4 = *(const uint4*)(qp + quad * 8);
    qf[1].u4 = *(const uint4*)(qp + 32 + quad * 8);
  }

  // stage 128-key K/V tile KT into buffer (KT&1): linear LDS dest, swizzled global source
#define STAGE_KV(KT) do { \
    const int bo_ = ((KT) & 1) * 8192; \
    const bf16* kg_ = Kbase + (size_t)((KT) * 128 + wid * 16 + rl) * nD + cg8; \
    gload_lds16(kg_, lds_buf + bo_ + wid * 1024); \
    gload_lds16(kg_ + (size_t)8 * nD, lds_buf + bo_ + wid * 1024 + 512); \
    const bf16* vg_ = Vbase + (size_t)(wid * 8 + rl) * nS + (KT) * 128 + cg8; \
    gload_lds16(vg_, lds_buf + 16384 + bo_ + wid * 512); \
    gload_lds16(vg_ + 64, lds_buf + 16384 + bo_ + 4096 + wid * 512); \
  } while (0)

  // QK^T for half HB of current K tile -> ST (S^T frags, key=row)
#define QKH(Kb, HB, ST) do { \
    _Pragma("unroll") \
    for (int kt4 = 0; kt4 < 4; ++kt4) { \
      int row = (HB) * 64 + kt4 * 16 + l16; \
      Frag16B k0_, k1_; \
      k0_.u4 = *(const uint4*)&(Kb)[row * 64 + ((quad ^ r7) * 8)]; \
      k1_.u4 = *(const uint4*)&(Kb)[row * 64 + (((quad + 4) ^ r7) * 8)]; \
      float4v zz_ = {}; \
      zz_ = __builtin_amdgcn_mfma_f32_16x16x32_bf16(k0_.v, qf[0].v, zz_, 0, 0, 0); \
      (ST)[kt4] = __builtin_amdgcn_mfma_f32_16x16x32_bf16(k1_.v, qf[1].v, zz_, 0, 0, 0); \
    } \
  } while (0)

  // exp (unmasked) ST -> PF (Q pre-scaled; l handled by MFMA ones-trick in PVH)
#define EXPH(ST, PF) do { \
    _Pragma("unroll") \
    for (int kt4 = 0; kt4 < 4; ++kt4) \
      _Pragma("unroll") \
      for (int r = 0; r < 4; ++r) { \
        float p_ = fast_exp2((ST)[kt4][r]); \
        union { bf16 hh; short ss; } cv_; \
        cv_.hh = __float2bfloat16(p_); \
        (PF)[kt4][r] = cv_.ss; \
      } \
  } while (0)

  // exp (masked, diagonal tile) for half HB
#define EXPHM(ST, PF, HB) do { \
    int qg_ = q0w + l16; \
    _Pragma("unroll") \
    for (int kt4 = 0; kt4 < 4; ++kt4) { \
      int key0_ = qt * 128 + (HB) * 64 + kt4 * 16 + quad * 4; \
      _Pragma("unroll") \
      for (int r = 0; r < 4; ++r) { \
        float x_ = (ST)[kt4][r]; \
        if (key0_ + r > qg_) x_ = -12000.0f; \
        float p_ = fast_exp2(x_); \
        union { bf16 hh; short ss; } cv_; \
        cv_.hh = __float2bfloat16(p_); \
        (PF)[kt4][r] = cv_.ss; \
      } \
    } \
  } while (0)

  // O^T += V^T(half HB) . P^T ; plus l-row via ones MFMA (every C row = sum_k P[k][q])
#define PVH(Vb, HB, PF) do { \
    _Pragma("unroll") \
    for (int dt = 0; dt < 4; ++dt) { \
      int row = dt * 16 + l16; \
      _Pragma("unroll") \
      for (int kt4 = 0; kt4 < 4; ++kt4) { \
        int chunk_ = kt4 * 2 + (quad >> 1); \
        union { uint2 u; short4v s; } vv_; \
        vv_.u = *(const uint2*)&(Vb)[(HB) * 4096 + row * 64 + ((chunk_ ^ r7) * 8) + (quad & 1) * 4]; \
        o_acc[dt] = __builtin_amdgcn_mfma_f32_16x16x16bf16_1k(vv_.s, (PF)[kt4], o_acc[dt], 0, 0, 0); \
      } \
    } \
    _Pragma("unroll") \
    for (int kt4 = 0; kt4 < 4; ++kt4) \
      o_l = __builtin_amdgcn_mfma_f32_16x16x16bf16_1k(vones, (PF)[kt4], o_l, 0, 0, 0); \
  } while (0)

  STAGE_KV(0);
  asm volatile("s_waitcnt vmcnt(0)" ::: "memory");
  __builtin_amdgcn_s_barrier();

  float4v o_acc[4] = {};
  float4v o_l = {};

  // ---- main loop: full unmasked tiles (branchless)
  for (int kt = 0; kt < qt; ++kt) {
    STAGE_KV(kt + 1);
    const bf16* Kb = lds_buf + (kt & 1) * 8192;
    const bf16* Vb = lds_buf + 16384 + (kt & 1) * 8192;

    float4v st0[4], st1[4];
    __builtin_amdgcn_s_setprio(1);
    QKH(Kb, 0, st0);
    QKH(Kb, 1, st1);
    __builtin_amdgcn_s_setprio(0);

    short4v pf[4];
    EXPH(st0, pf);
    __builtin_amdgcn_s_setprio(1);
    PVH(Vb, 0, pf);
    __builtin_amdgcn_s_setprio(0);
    EXPH(st1, pf);
    __builtin_amdgcn_s_setprio(1);
    PVH(Vb, 1, pf);
    __builtin_amdgcn_s_setprio(0);

    asm volatile("s_waitcnt vmcnt(0) lgkmcnt(0)" ::: "memory");
    __builtin_amdgcn_s_barrier();
  }

  // ---- final diagonal tile kt = qt (no prefetch; all masking lives here)
  {
    const bf16* Kb = lds_buf + (qt & 1) * 8192;
    const bf16* Vb = lds_buf + 16384 + (qt & 1) * 8192;

    float4v st0[4];
    QKH(Kb, 0, st0);
    short4v pf[4];
    EXPHM(st0, pf, 0);
    PVH(Vb, 0, pf);

    if (wid >= 4) {   // waves 0-3: h1 keys are all > q0w+15 (fully masked) -> skip
      float4v st1[4];
      QKH(Kb, 1, st1);
      EXPHM(st1, pf, 1);
      PVH(Vb, 1, pf);
    }
  }
#undef STAGE_KV
#undef QKH
#undef EXPH
#undef EXPHM
#undef PVH

  // all waves done reading K/V before scratch (overlapping K region) is overwritten
  lds_barrier();

  // ---- epilogue: LDS-transpose, coalesced 16B stores (l already complete per-lane in o_l[0])
  float inv_l = 1.0f / o_l[0];
  // write transposed: scratch[q_loc=l16][d]
#pragma unroll
  for (int dt = 0; dt < 4; ++dt) {
    union { bf16 b2[2]; uint u; } p01, p23;
    p01.b2[0] = __float2bfloat16(o_acc[dt][0] * inv_l);
    p01.b2[1] = __float2bfloat16(o_acc[dt][1] * inv_l);
    p23.b2[0] = __float2bfloat16(o_acc[dt][2] * inv_l);
    p23.b2[1] = __float2bfloat16(o_acc[dt][3] * inv_l);
    *(uint*)&scratch[l16 * 72 + dt * 16 + quad * 4] = p01.u;
    *(uint*)&scratch[l16 * 72 + dt * 16 + quad * 4 + 2] = p23.u;
  }
  lgkm_wait();  // own writes visible to own reads
  uint4 r0 = *(const uint4*)&scratch[l16 * 72 + quad * 16];
  uint4 r1 = *(const uint4*)&scratch[l16 * 72 + quad * 16 + 8];
  int qrow = q0w + l16;
  bf16* vp = vals + ((size_t)(b * nS + qrow)) * nD + h * 64 + quad * 16;
  *(uint4*)(vp) = r0;
  *(uint4*)(vp + 8) = r1;
}

// ---------------------------------------------------------------- launch
extern "C" void kernel_launch(void* const* d_in, const int* in_sizes, int n_in,
                              void* d_out, int out_size, void* d_ws, size_t ws_size,
                              hipStream_t stream) {
  const float* Qin = (const float*)d_in[0];
  const float* Kin = (const float*)d_in[1];
  const float* Vin = (const float*)d_in[2];
  const float* Wq = (const float*)d_in[4];
  const float* Wk = (const float*)d_in[5];
  const float* Wv = (const float*)d_in[6];
  const float* Wo = (const float*)d_in[7];
  float* out = (float*)d_out;

  char* ws = (char*)d_ws;
  const size_t MB = 1u << 20;
  bf16* Qbf = (bf16*)(ws + 0 * MB);
  bf16* Kbf = (bf16*)(ws + 8 * MB);
  bf16* Vbf = (bf16*)(ws + 16 * MB);
  bf16* WqT = (bf16*)(ws + 24 * MB);
  bf16* WkT = (bf16*)(ws + 26 * MB);
  bf16* WvT = (bf16*)(ws + 28 * MB);
  bf16* WoT = (bf16*)(ws + 30 * MB);
  bf16* cos_t = (bf16*)(ws + 32 * MB);
  bf16* sin_t = (bf16*)(ws + 33 * MB);
  bf16* q_h = (bf16*)(ws + 34 * MB);
  bf16* k_h = (bf16*)(ws + 42 * MB);
  bf16* vt_h = (bf16*)(ws + 50 * MB);
  bf16* vals = (bf16*)(ws + 58 * MB);

  prep_kernel<<<4160, 256, 0, stream>>>(Qin, Kin, Vin, Wq, Wk, Wv, Wo,
                                        Qbf, Kbf, Vbf, WqT, WkT, WvT, WoT, cos_t, sin_t);

  gemm_qkv_kernel<<<768, 256, 0, stream>>>(Qbf, Kbf, Vbf, WqT, WkT, WvT,
                                           q_h, k_h, vt_h, cos_t, sin_t);

  attn_kernel<<<512, 512, 0, stream>>>(q_h, k_h, vt_h, vals);

  gemm_out_kernel<<<512, 256, 0, stream>>>(vals, WoT, out);
}

// Round 14
// 199.190 us; speedup vs baseline: 1.0873x; 1.0153x over previous
//
#include <hip/hip_runtime.h>
#include <hip/hip_bf16.h>
#include <stdint.h>

typedef __hip_bfloat16 bf16;
typedef __attribute__((ext_vector_type(8))) short short8;
typedef __attribute__((ext_vector_type(4))) short short4v;
typedef __attribute__((ext_vector_type(4))) float float4v;

static constexpr int nB = 2, nS = 2048, nD = 1024, nH = 16, nHD = 64;
static constexpr int nBS = nB * nS;   // 4096

#define AS_GLOBAL __attribute__((address_space(1)))
#define AS_LDS    __attribute__((address_space(3)))

union Frag16B { short8 v; uint4 u4; uint2 u2[2]; };

__device__ __forceinline__ void gload_lds16(const void* g, void* l) {
  __builtin_amdgcn_global_load_lds((AS_GLOBAL uint32_t*)(g), (AS_LDS uint32_t*)(l), 16, 0, 0);
}

__device__ __forceinline__ float fast_exp2(float x) {
#if __has_builtin(__builtin_amdgcn_exp2f)
  return __builtin_amdgcn_exp2f(x);
#else
  float r; asm volatile("v_exp_f32 %0, %1" : "=v"(r) : "v"(x)); return r;
#endif
}

// drain LDS ops but NOT vmem: prefetch global loads stay in flight across the barrier
__device__ __forceinline__ void lds_barrier() {
  asm volatile("s_waitcnt lgkmcnt(0)\ns_barrier" ::: "memory");
}

__device__ __forceinline__ void lgkm_wait() {
  asm volatile("s_waitcnt lgkmcnt(0)" ::: "memory");
}

static constexpr float SC = 0.18033688011112042f;  // 0.125 * log2(e), folded into Q at projection

// ---------------------------------------------------------------- prep: cast QKV->bf16, W->W^T bf16, rope tables
__global__ __launch_bounds__(256) void prep_kernel(
    const float* __restrict__ Qin, const float* __restrict__ Kin, const float* __restrict__ Vin,
    const float* __restrict__ Wq, const float* __restrict__ Wk,
    const float* __restrict__ Wv, const float* __restrict__ Wo,
    bf16* __restrict__ Qbf, bf16* __restrict__ Kbf, bf16* __restrict__ Vbf,
    bf16* __restrict__ WqT, bf16* __restrict__ WkT, bf16* __restrict__ WvT, bf16* __restrict__ WoT,
    bf16* __restrict__ cos_t, bf16* __restrict__ sin_t) {
  __shared__ float tile[64][65];
  int bx = blockIdx.x, t = threadIdx.x;
  if (bx < 3072) {
    int tz = bx >> 10, blk = bx & 1023;
    const float* src = tz == 0 ? Qin : tz == 1 ? Kin : Vin;
    bf16* dst = tz == 0 ? Qbf : tz == 1 ? Kbf : Vbf;
#pragma unroll
    for (int i = 0; i < 4; ++i) {
      int idx = blk * 1024 + i * 256 + t;  // float4 index
      float4 v = ((const float4*)src)[idx];
      union { bf16 b[4]; uint2 u; } tmp;
      tmp.b[0] = __float2bfloat16(v.x);
      tmp.b[1] = __float2bfloat16(v.y);
      tmp.b[2] = __float2bfloat16(v.z);
      tmp.b[3] = __float2bfloat16(v.w);
      ((uint2*)dst)[idx] = tmp.u;
    }
  } else if (bx < 4096) {
    int idx = bx - 3072;
    int z = idx >> 8;
    const float* W = z == 0 ? Wq : z == 1 ? Wk : z == 2 ? Wv : Wo;
    bf16* T = z == 0 ? WqT : z == 1 ? WkT : z == 2 ? WvT : WoT;
    int tk = (idx & 15) * 64, tn = ((idx >> 4) & 15) * 64;
    int c = t & 63, r0 = t >> 6;
#pragma unroll
    for (int i = 0; i < 16; ++i) {
      int r = i * 4 + r0;
      tile[r][c] = W[(size_t)(tk + r) * nD + tn + c];
    }
    __syncthreads();
#pragma unroll
    for (int i = 0; i < 16; ++i) {
      int r = i * 4 + r0;
      T[(size_t)(tn + r) * nD + tk + c] = __float2bfloat16(tile[c][r]);
    }
  } else {
    int base = (bx - 4096) * 1024 + t * 4;
#pragma unroll
    for (int i = 0; i < 4; ++i) {
      int e = base + i;
      int s = e >> 5, j = e & 31;
      float inv_freq = powf(100000.0f, -(float)(2 * j) / 64.0f);
      float g = (float)s * inv_freq;
      cos_t[e] = __float2bfloat16(cosf(g));
      sin_t[e] = __float2bfloat16(sinf(g));
    }
  }
}

// ---------------------------------------------------------------- fused projection GEMM v6: m97-faithful + 4 blocks/CU.
__global__ __launch_bounds__(256, 4) void gemm_qkv_kernel(
    const bf16* __restrict__ A0, const bf16* __restrict__ A1, const bf16* __restrict__ A2,
    const bf16* __restrict__ Bt0, const bf16* __restrict__ Bt1, const bf16* __restrict__ Bt2,
    bf16* __restrict__ q_h, bf16* __restrict__ k_h, bf16* __restrict__ vt_h,
    const bf16* __restrict__ cos_t, const bf16* __restrict__ sin_t) {
  const int bid = blockIdx.x;
  const int swz = (bid & 7) * 96 + (bid >> 3);
  const int z = swz >> 8;            // 0..2
  const int rem = swz & 255;
  const int n0 = (rem >> 5) * 128;   // 8 n-tiles
  const int m0 = (rem & 31) * 128;   // 32 m-tiles

  const bf16* __restrict__ A  = z == 0 ? A0 : (z == 1 ? A1 : A2);
  const bf16* __restrict__ Bt = z == 0 ? Bt0 : (z == 1 ? Bt1 : Bt2);

  __shared__ bf16 As[128 * 64];   // 16 KiB
  __shared__ bf16 Bs[128 * 64];   // 16 KiB

  const int t = threadIdx.x;          // 0..255
  const int lane = t & 63;
  const int wid = t >> 6;             // 0..3
  const int quad = lane >> 4;
  const int l16 = lane & 15;
  const int r7 = l16 & 7;
  const int wm = wid >> 1;            // 0..1 -> 64 rows each
  const int wn = wid & 1;             // 0..1 -> 64 cols each (one head per wave)

  const int srow = t >> 3;                       // 0..31
  const int scg8 = ((t & 7) ^ (srow & 7)) * 8;   // swizzled k-offset (elements)

  const int ch0 = (quad ^ r7) * 8;
  const int ch1 = ch0 ^ 32;
  const int arow = (wm * 64 + l16) * 64;   // + mi*1024
  const int brow = (wn * 64 + l16) * 64;   // + ni*1024

  float4v acc[4][4] = {};

  for (int T = 0; T < 16; ++T) {
    {
      const bf16* ag_ = A + (size_t)(m0 + srow) * nD + T * 64 + scg8;
      const bf16* bg_ = Bt + (size_t)(n0 + srow) * nD + T * 64 + scg8;
#pragma unroll
      for (int i = 0; i < 4; ++i) {
        gload_lds16(ag_ + (size_t)(i * 32) * nD, As + i * 2048 + wid * 512);
        gload_lds16(bg_ + (size_t)(i * 32) * nD, Bs + i * 2048 + wid * 512);
      }
    }
    asm volatile("s_waitcnt vmcnt(0)" ::: "memory");
    __builtin_amdgcn_s_barrier();

    // ---- kk0 half
    Frag16B fa[4], fb[4];
#pragma unroll
    for (int mi = 0; mi < 4; ++mi) fa[mi].u4 = *(const uint4*)&As[arow + mi * 1024 + ch0];
#pragma unroll
    for (int ni = 0; ni < 4; ++ni) fb[ni].u4 = *(const uint4*)&Bs[brow + ni * 1024 + ch0];
    __builtin_amdgcn_s_setprio(1);
#pragma unroll
    for (int mi = 0; mi < 4; ++mi)
#pragma unroll
      for (int ni = 0; ni < 4; ++ni)
        acc[mi][ni] = __builtin_amdgcn_mfma_f32_16x16x32_bf16(fa[mi].v, fb[ni].v, acc[mi][ni], 0, 0, 0);
    __builtin_amdgcn_s_setprio(0);

    // ---- kk1 half
#pragma unroll
    for (int mi = 0; mi < 4; ++mi) fa[mi].u4 = *(const uint4*)&As[arow + mi * 1024 + ch1];
#pragma unroll
    for (int ni = 0; ni < 4; ++ni) fb[ni].u4 = *(const uint4*)&Bs[brow + ni * 1024 + ch1];
    __builtin_amdgcn_s_setprio(1);
#pragma unroll
    for (int mi = 0; mi < 4; ++mi)
#pragma unroll
      for (int ni = 0; ni < 4; ++ni)
        acc[mi][ni] = __builtin_amdgcn_mfma_f32_16x16x32_bf16(fa[mi].v, fb[ni].v, acc[mi][ni], 0, 0, 0);
    __builtin_amdgcn_s_setprio(0);

    __builtin_amdgcn_s_barrier();
  }

  // ---- epilogue: RoPE + RMSNorm (q,k) or transposed store (v)
  const int col0 = n0 + wn * 64;   // multiple of 64 -> one head per wave
  if (z <= 1) {
    bf16* dst = z ? k_h : q_h;
#pragma unroll
    for (int mi = 0; mi < 4; ++mi)
#pragma unroll
      for (int r = 0; r < 4; ++r) {
        int row = m0 + wm * 64 + mi * 16 + quad * 4 + r;
        int s = row & (nS - 1);
        float x0 = acc[mi][0][r], x1 = acc[mi][1][r], x2 = acc[mi][2][r], x3 = acc[mi][3][r];
        float y[4];
#pragma unroll
        for (int p = 0; p < 2; ++p) {
          int d = p * 16 + l16;
          float c = __bfloat162float(cos_t[s * 32 + d]);
          float sn = __bfloat162float(sin_t[s * 32 + d]);
          float xa = p ? x1 : x0, xb = p ? x3 : x2;
          y[p] = xa * c + xb * sn;
          y[p + 2] = xb * c - xa * sn;
        }
        float ss = y[0] * y[0] + y[1] * y[1] + y[2] * y[2] + y[3] * y[3];
#pragma unroll
        for (int m = 1; m <= 8; m <<= 1) ss += __shfl_xor(ss, m, 64);
        float inv = 1.0f / sqrtf(ss * (1.0f / 64.0f) + 1e-9f);
        if (z == 0) inv *= SC;   // fold attention scale*log2e into Q (f32-exact)
#pragma unroll
        for (int ni = 0; ni < 4; ++ni)
          dst[(size_t)row * nD + col0 + ni * 16 + l16] = __float2bfloat16(y[ni] * inv);
      }
  } else {
    // V: write transposed -> vt_h [b][h][d][s]
#pragma unroll
    for (int mi = 0; mi < 4; ++mi)
#pragma unroll
      for (int r = 0; r < 4; ++r) {
        int row = m0 + wm * 64 + mi * 16 + quad * 4 + r;
        int b = row >> 11, s = row & (nS - 1);
#pragma unroll
        for (int ni = 0; ni < 4; ++ni) {
          int col = col0 + ni * 16 + l16;
          int h = col >> 6, d = col & 63;
          vt_h[((size_t)((b * nH + h) * 64 + d)) * nS + s] = __float2bfloat16(acc[mi][ni][r]);
        }
      }
  }
}

// ---------------------------------------------------------------- output GEMM v3: 64x128 tile, BK=64,
// double-buffered 48 KiB LDS, ONE barrier per K-step, 3 blocks/CU.
__global__ __launch_bounds__(256, 3) void gemm_out_kernel(
    const bf16* __restrict__ A, const bf16* __restrict__ Bt, float* __restrict__ C) {
  __shared__ bf16 As[2 * 64 * 64];    // 16 KiB
  __shared__ bf16 Bs[2 * 128 * 64];   // 32 KiB
  const int bid = blockIdx.x;         // 0..511
  const int n0 = (bid & 7) * 128;
  const int m0 = (bid >> 3) * 64;
  const int t = threadIdx.x;
  const int lane = t & 63;
  const int wid = t >> 6;
  const int quad = lane >> 4;
  const int l16 = lane & 15;
  const int r7 = l16 & 7;
  const int wm = wid >> 1;
  const int wn = wid & 1;

  const int srow = t >> 3;                       // 0..31
  const int scg8 = ((t & 7) ^ (srow & 7)) * 8;

  const int ch0 = (quad ^ r7) * 8;
  const int ch1 = ch0 ^ 32;
  const int arow = (wm * 32 + l16) * 64;   // + mi*1024 (+buf)
  const int brow = (wn * 64 + l16) * 64;   // + ni*1024 (+buf)

#define STAGE_O(KT, AB, BB) do { \
    const bf16* ag_ = A + (size_t)(m0 + srow) * nD + (KT) * 64 + scg8; \
    const bf16* bg_ = Bt + (size_t)(n0 + srow) * nD + (KT) * 64 + scg8; \
    gload_lds16(ag_, As + (AB) + wid * 512); \
    gload_lds16(ag_ + (size_t)32 * nD, As + (AB) + 2048 + wid * 512); \
    _Pragma("unroll") \
    for (int i = 0; i < 4; ++i) \
      gload_lds16(bg_ + (size_t)(i * 32) * nD, Bs + (BB) + i * 2048 + wid * 512); \
  } while (0)

  float4v acc[2][4] = {};

  STAGE_O(0, 0, 0);
  asm volatile("s_waitcnt vmcnt(0)" ::: "memory");
  __builtin_amdgcn_s_barrier();

#pragma unroll 2
  for (int T = 0; T < 16; ++T) {
    const int cua = (T & 1) * 4096;
    const int cub = (T & 1) * 8192;

    if (T < 15) STAGE_O(T + 1, cua ^ 4096, cub ^ 8192);

    Frag16B a0[2], a1[2], b0[4], b1[4];
#pragma unroll
    for (int mi = 0; mi < 2; ++mi) {
      a0[mi].u4 = *(const uint4*)&As[cua + arow + mi * 1024 + ch0];
      a1[mi].u4 = *(const uint4*)&As[cua + arow + mi * 1024 + ch1];
    }
#pragma unroll
    for (int ni = 0; ni < 4; ++ni) {
      b0[ni].u4 = *(const uint4*)&Bs[cub + brow + ni * 1024 + ch0];
      b1[ni].u4 = *(const uint4*)&Bs[cub + brow + ni * 1024 + ch1];
    }

    __builtin_amdgcn_s_setprio(1);
#pragma unroll
    for (int mi = 0; mi < 2; ++mi)
#pragma unroll
      for (int ni = 0; ni < 4; ++ni)
        acc[mi][ni] = __builtin_amdgcn_mfma_f32_16x16x32_bf16(a0[mi].v, b0[ni].v, acc[mi][ni], 0, 0, 0);
#pragma unroll
    for (int mi = 0; mi < 2; ++mi)
#pragma unroll
      for (int ni = 0; ni < 4; ++ni)
        acc[mi][ni] = __builtin_amdgcn_mfma_f32_16x16x32_bf16(a1[mi].v, b1[ni].v, acc[mi][ni], 0, 0, 0);
    __builtin_amdgcn_s_setprio(0);

    asm volatile("s_waitcnt vmcnt(0)" ::: "memory");
    __builtin_amdgcn_s_barrier();
  }
#undef STAGE_O

#pragma unroll
  for (int mi = 0; mi < 2; ++mi)
#pragma unroll
    for (int ni = 0; ni < 4; ++ni)
#pragma unroll
      for (int r = 0; r < 4; ++r) {
        int row = m0 + wm * 32 + mi * 16 + quad * 4 + r;
        int col = n0 + wn * 64 + ni * 16 + l16;
        C[(size_t)row * nD + col] = acc[mi][ni][r];
      }
}

// ---------------------------------------------------------------- flash attention v10: 4-wave 256-thread blocks,
// 64-row q-tiles (32 per head) -> grid 1024, 2x oversubscribed, LPT (longest first), XCD-pinned heads.
// SINGLE-buffered 32 KiB LDS [K 128x64 | V 2x 64x64], m97-style 2-barrier loop per 128-key tile:
//   stage -> vmcnt(0) -> barrier -> compute (HB0 then HB1) -> barrier
// Cross-block TLP (4 blocks/CU, launch_bounds(256,4), 128 KiB LDS) hides the drain — the exact
// schedule proven in gemm_qkv. Masking: full tiles branchless; final tile handles diagonal
// (odd qt': HB0 unmasked + HB1 masked; even qt': HB0 masked, HB1 skipped — block-uniform).
// Q pre-scaled by SC; l via MFMA ones-trick.
__global__ __launch_bounds__(256, 4) void attn_kernel(const bf16* __restrict__ q_h,
                                                      const bf16* __restrict__ k_h,
                                                      const bf16* __restrict__ vt_h,
                                                      bf16* __restrict__ vals) {
  __shared__ bf16 lds_buf[16384];      // [K: 0..8191 | V_HB0: 8192..12287 | V_HB1: 12288..16383]

  const int t = threadIdx.x;           // 0..255
  const int lane = t & 63, wid = t >> 6, quad = lane >> 4, l16 = lane & 15;
  const int id = blockIdx.x;           // 0..1023
  const int xcd = id & 7;
  const int j = id >> 3;               // 0..127
  const int bh = xcd * 4 + (j & 3);    // head pinned to XCD
  const int qt = 31 - (j >> 2);        // 64-row q-tile index, LPT: longest first
  const int b = bh >> 4, h = bh & 15;

  const int nfull = qt >> 1;           // full unmasked 128-key tiles

  const bf16* Kbase = k_h + ((size_t)b * nS) * nD + h * 64;
  const bf16* Vbase = vt_h + (size_t)bh * 64 * nS;  // [d][s]

  const int rl = lane >> 3;               // 0..7
  const int cg8 = ((lane & 7) ^ rl) * 8;  // pre-swizzled source chunk (elem offset)
  const int r7 = l16 & 7;

  bf16* const scratch = lds_buf + wid * 1152;  // 16 x 72 per wave (epilogue only)

  const int q0w = qt * 64 + wid * 16;     // wave's first q row

  const short4v vones = {(short)0x3F80, (short)0x3F80, (short)0x3F80, (short)0x3F80};  // bf16 1.0 x4

  // Q B-frags (col=q=l16, k=d), 2 d-halves
  Frag16B qf[2];
  {
    const bf16* qp = q_h + ((size_t)(b * nS + q0w + l16)) * nD + h * 64;
    qf[0].u4 = *(const uint4*)(qp + quad * 8);
    qf[1].u4 = *(const uint4*)(qp + 32 + quad * 8);
  }

  // stage 128-key K/V tile KT into the single buffer: linear LDS dest, swizzled global source.
  // K: wave wid covers rows wid*32 + i*8 + rl (i=0..3). V: d-rows wid*16 + i*8 + rl (i=0..1), 2 s-halves.
#define STAGE_KV(KT) do { \
    const bf16* kg_ = Kbase + (size_t)((KT) * 128 + wid * 32 + rl) * nD + cg8; \
    gload_lds16(kg_, lds_buf + wid * 2048); \
    gload_lds16(kg_ + (size_t)8 * nD, lds_buf + wid * 2048 + 512); \
    gload_lds16(kg_ + (size_t)16 * nD, lds_buf + wid * 2048 + 1024); \
    gload_lds16(kg_ + (size_t)24 * nD, lds_buf + wid * 2048 + 1536); \
    const bf16* vg_ = Vbase + (size_t)(wid * 16 + rl) * nS + (KT) * 128 + cg8; \
    gload_lds16(vg_, lds_buf + 8192 + wid * 1024); \
    gload_lds16(vg_ + 64, lds_buf + 12288 + wid * 1024); \
    gload_lds16(vg_ + (size_t)8 * nS, lds_buf + 8192 + wid * 1024 + 512); \
    gload_lds16(vg_ + (size_t)8 * nS + 64, lds_buf + 12288 + wid * 1024 + 512); \
  } while (0)

  // QK^T for half HB of the staged tile -> ST (S^T frags, key=row)
#define QKH(HB, ST) do { \
    _Pragma("unroll") \
    for (int kt4 = 0; kt4 < 4; ++kt4) { \
      int row = (HB) * 64 + kt4 * 16 + l16; \
      Frag16B k0_, k1_; \
      k0_.u4 = *(const uint4*)&lds_buf[row * 64 + ((quad ^ r7) * 8)]; \
      k1_.u4 = *(const uint4*)&lds_buf[row * 64 + (((quad + 4) ^ r7) * 8)]; \
      float4v zz_ = {}; \
      zz_ = __builtin_amdgcn_mfma_f32_16x16x32_bf16(k0_.v, qf[0].v, zz_, 0, 0, 0); \
      (ST)[kt4] = __builtin_amdgcn_mfma_f32_16x16x32_bf16(k1_.v, qf[1].v, zz_, 0, 0, 0); \
    } \
  } while (0)

  // exp (unmasked) ST -> PF (Q pre-scaled; l via ones-trick in PVH)
#define EXPH(ST, PF) do { \
    _Pragma("unroll") \
    for (int kt4 = 0; kt4 < 4; ++kt4) \
      _Pragma("unroll") \
      for (int r = 0; r < 4; ++r) { \
        float p_ = fast_exp2((ST)[kt4][r]); \
        union { bf16 hh; short ss; } cv_; \
        cv_.hh = __float2bfloat16(p_); \
        (PF)[kt4][r] = cv_.ss; \
      } \
  } while (0)

  // exp (masked, diagonal tile) for half HB of tile nfull
#define EXPHM(ST, PF, HB) do { \
    int qg_ = q0w + l16; \
    _Pragma("unroll") \
    for (int kt4 = 0; kt4 < 4; ++kt4) { \
      int key0_ = nfull * 128 + (HB) * 64 + kt4 * 16 + quad * 4; \
      _Pragma("unroll") \
      for (int r = 0; r < 4; ++r) { \
        float x_ = (ST)[kt4][r]; \
        if (key0_ + r > qg_) x_ = -12000.0f; \
        float p_ = fast_exp2(x_); \
        union { bf16 hh; short ss; } cv_; \
        cv_.hh = __float2bfloat16(p_); \
        (PF)[kt4][r] = cv_.ss; \
      } \
    } \
  } while (0)

  // O^T += V^T(half HB) . P^T ; l-row via ones MFMA
#define PVH(HB, PF) do { \
    const bf16* Vb_ = lds_buf + 8192 + (HB) * 4096; \
    _Pragma("unroll") \
    for (int dt = 0; dt < 4; ++dt) { \
      int row = dt * 16 + l16; \
      _Pragma("unroll") \
      for (int kt4 = 0; kt4 < 4; ++kt4) { \
        int chunk_ = kt4 * 2 + (quad >> 1); \
        union { uint2 u; short4v s; } vv_; \
        vv_.u = *(const uint2*)&Vb_[row * 64 + ((chunk_ ^ r7) * 8) + (quad & 1) * 4]; \
        o_acc[dt] = __builtin_amdgcn_mfma_f32_16x16x16bf16_1k(vv_.s, (PF)[kt4], o_acc[dt], 0, 0, 0); \
      } \
    } \
    _Pragma("unroll") \
    for (int kt4 = 0; kt4 < 4; ++kt4) \
      o_l = __builtin_amdgcn_mfma_f32_16x16x16bf16_1k(vones, (PF)[kt4], o_l, 0, 0, 0); \
  } while (0)

  float4v o_acc[4] = {};
  float4v o_l = {};

  // ---- full unmasked tiles: stage -> drain -> bar -> compute -> bar
  for (int kt = 0; kt < nfull; ++kt) {
    STAGE_KV(kt);
    asm volatile("s_waitcnt vmcnt(0)" ::: "memory");
    __builtin_amdgcn_s_barrier();

    float4v st[4];
    short4v pf[4];
    __builtin_amdgcn_s_setprio(1);
    QKH(0, st);
    __builtin_amdgcn_s_setprio(0);
    EXPH(st, pf);
    __builtin_amdgcn_s_setprio(1);
    PVH(0, pf);
    QKH(1, st);
    __builtin_amdgcn_s_setprio(0);
    EXPH(st, pf);
    __builtin_amdgcn_s_setprio(1);
    PVH(1, pf);
    __builtin_amdgcn_s_setprio(0);

    lds_barrier();   // all waves done reading before next stage overwrites
  }

  // ---- final tile kt = nfull: diagonal handling (block-uniform branches, no inner barriers)
  {
    STAGE_KV(nfull);
    asm volatile("s_waitcnt vmcnt(0)" ::: "memory");
    __builtin_amdgcn_s_barrier();

    float4v st[4];
    short4v pf[4];
    if (qt & 1) {
      QKH(0, st);
      EXPH(st, pf);      // keys (qt-1)*64..qt*64-1 all <= q rows qt*64.. -> unmasked
      PVH(0, pf);
      QKH(1, st);
      EXPHM(st, pf, 1);  // diagonal
      PVH(1, pf);
    } else {
      QKH(0, st);
      EXPHM(st, pf, 0);  // diagonal
      PVH(0, pf);
      // HB1 keys all > q rows -> fully masked -> skip (block-uniform)
    }
  }
#undef STAGE_KV
#undef QKH
#undef EXPH
#undef EXPHM
#undef PVH

  // all waves done reading K/V before scratch (K region) is overwritten
  lds_barrier();

  // ---- epilogue: LDS-transpose, coalesced 16B stores (l complete per-lane in o_l[0])
  float inv_l = 1.0f / o_l[0];
#pragma unroll
  for (int dt = 0; dt < 4; ++dt) {
    union { bf16 b2[2]; uint u; } p01, p23;
    p01.b2[0] = __float2bfloat16(o_acc[dt][0] * inv_l);
    p01.b2[1] = __float2bfloat16(o_acc[dt][1] * inv_l);
    p23.b2[0] = __float2bfloat16(o_acc[dt][2] * inv_l);
    p23.b2[1] = __float2bfloat16(o_acc[dt][3] * inv_l);
    *(uint*)&scratch[l16 * 72 + dt * 16 + quad * 4] = p01.u;
    *(uint*)&scratch[l16 * 72 + dt * 16 + quad * 4 + 2] = p23.u;
  }
  lgkm_wait();  // own writes visible to own reads
  uint4 r0 = *(const uint4*)&scratch[l16 * 72 + quad * 16];
  uint4 r1 = *(const uint4*)&scratch[l16 * 72 + quad * 16 + 8];
  int qrow = q0w + l16;
  bf16* vp = vals + ((size_t)(b * nS + qrow)) * nD + h * 64 + quad * 16;
  *(uint4*)(vp) = r0;
  *(uint4*)(vp + 8) = r1;
}

// ---------------------------------------------------------------- launch
extern "C" void kernel_launch(void* const* d_in, const int* in_sizes, int n_in,
                              void* d_out, int out_size, void* d_ws, size_t ws_size,
                              hipStream_t stream) {
  const float* Qin = (const float*)d_in[0];
  const float* Kin = (const float*)d_in[1];
  const float* Vin = (const float*)d_in[2];
  const float* Wq = (const float*)d_in[4];
  const float* Wk = (const float*)d_in[5];
  const float* Wv = (const float*)d_in[6];
  const float* Wo = (const float*)d_in[7];
  float* out = (float*)d_out;

  char* ws = (char*)d_ws;
  const size_t MB = 1u << 20;
  bf16* Qbf = (bf16*)(ws + 0 * MB);
  bf16* Kbf = (bf16*)(ws + 8 * MB);
  bf16* Vbf = (bf16*)(ws + 16 * MB);
  bf16* WqT = (bf16*)(ws + 24 * MB);
  bf16* WkT = (bf16*)(ws + 26 * MB);
  bf16* WvT = (bf16*)(ws + 28 * MB);
  bf16* WoT = (bf16*)(ws + 30 * MB);
  bf16* cos_t = (bf16*)(ws + 32 * MB);
  bf16* sin_t = (bf16*)(ws + 33 * MB);
  bf16* q_h = (bf16*)(ws + 34 * MB);
  bf16* k_h = (bf16*)(ws + 42 * MB);
  bf16* vt_h = (bf16*)(ws + 50 * MB);
  bf16* vals = (bf16*)(ws + 58 * MB);

  prep_kernel<<<4160, 256, 0, stream>>>(Qin, Kin, Vin, Wq, Wk, Wv, Wo,
                                        Qbf, Kbf, Vbf, WqT, WkT, WvT, WoT, cos_t, sin_t);

  gemm_qkv_kernel<<<768, 256, 0, stream>>>(Qbf, Kbf, Vbf, WqT, WkT, WvT,
                                           q_h, k_h, vt_h, cos_t, sin_t);

  attn_kernel<<<1024, 256, 0, stream>>>(q_h, k_h, vt_h, vals);

  gemm_out_kernel<<<512, 256, 0, stream>>>(vals, WoT, out);
}